// Round 1
// baseline (1477.638 us; speedup 1.0000x reference)
//
#include <hip/hip_runtime.h>
#include <math.h>

#define NPIX 16384
#define CH 256
#define MDIM 32
#define NB 8
#define EPSF 1e-6f

// ws layout (float offsets)
#define OFF_Q    0ull          // [B][M][N]  8*32*16384 = 4194304
#define OFF_KV   4194304ull    // [B][M][C]  65536
#define OFF_KSUM 4259840ull    // [B][M]     256
#define OFF_EN   4260096ull    // [B][C][C]  524288
#define OFF_ATT  4784384ull    // [B][C(d)][C(c)] transposed attn, 524288
#define OFF_WVT  5308672ull    // [C(in)][C(out)] 65536

__global__ void k_transpose(const float* __restrict__ wv, float* __restrict__ wvT) {
    int o = blockIdx.x, d = threadIdx.x;
    wvT[d * CH + o] = wv[o * CH + d];
}

// Fused Q/K (softplus) conv + V conv + KV split-K accumulation + Ksum.
// grid (N/64, B), block 256.  LDS: xs 64K + ks 8K = 72K -> 2 blocks/CU.
__global__ __launch_bounds__(256, 2) void k_qkv(
    const float* __restrict__ x,
    const float* __restrict__ wq, const float* __restrict__ bq,
    const float* __restrict__ wk, const float* __restrict__ bk,
    const float* __restrict__ wvT, const float* __restrict__ bv,
    float* __restrict__ Q, float* __restrict__ KV, float* __restrict__ Ksum)
{
    __shared__ float xs[CH][64];
    __shared__ float ks[MDIM][64];
    const int b = blockIdx.y;
    const int n0 = blockIdx.x * 64;
    const int tid = threadIdx.x;
    const float* xb = x + (size_t)b * CH * NPIX;

    #pragma unroll
    for (int s = 0; s < 16; ++s) {
        int e4 = tid + s * 256;
        int c = e4 >> 4, j4 = e4 & 15;
        float4 v = *(const float4*)(xb + (size_t)c * NPIX + n0 + j4 * 4);
        *(float4*)&xs[c][j4 * 4] = v;
    }
    __syncthreads();

    {   // Q/K phase: wave w handles m = w*8..w*8+7, lane = pixel j
        const int j = tid & 63, mg = tid >> 6;
        float qa[8], ka[8];
        #pragma unroll
        for (int i = 0; i < 8; ++i) { qa[i] = bq[mg * 8 + i]; ka[i] = bk[mg * 8 + i]; }
        for (int d = 0; d < CH; ++d) {
            float xv = xs[d][j];
            #pragma unroll
            for (int i = 0; i < 8; ++i) {
                qa[i] = fmaf(wq[(mg * 8 + i) * CH + d], xv, qa[i]);
                ka[i] = fmaf(wk[(mg * 8 + i) * CH + d], xv, ka[i]);
            }
        }
        #pragma unroll
        for (int i = 0; i < 8; ++i) {
            int m = mg * 8 + i;
            float qv = qa[i], kv = ka[i];
            qv = fmaxf(qv, 0.f) + log1pf(expf(-fabsf(qv)));  // softplus
            kv = fmaxf(kv, 0.f) + log1pf(expf(-fabsf(kv)));
            Q[(size_t)(b * MDIM + m) * NPIX + n0 + j] = qv;
            ks[m][j] = kv;
        }
    }
    __syncthreads();

    if (tid < MDIM) {  // Ksum partial for this pixel tile
        float s = 0.f;
        #pragma unroll
        for (int j = 0; j < 64; ++j) s += ks[tid][j];
        atomicAdd(&Ksum[b * MDIM + tid], s);
    }

    // V phase: thread -> 4 out-channels (cg) x 16 pixels (pg)
    const int cg = tid >> 2, pg = tid & 3;
    float acc[4][16];
    #pragma unroll
    for (int i = 0; i < 4; ++i) {
        float bvv = bv[cg * 4 + i];
        #pragma unroll
        for (int u = 0; u < 16; ++u) acc[i][u] = bvv;
    }
    for (int d = 0; d < CH; ++d) {
        float4 w4 = *(const float4*)(wvT + d * CH + cg * 4);
        #pragma unroll
        for (int u = 0; u < 16; ++u) {
            float xv = xs[d][pg * 16 + u];
            acc[0][u] = fmaf(w4.x, xv, acc[0][u]);
            acc[1][u] = fmaf(w4.y, xv, acc[1][u]);
            acc[2][u] = fmaf(w4.z, xv, acc[2][u]);
            acc[3][u] = fmaf(w4.w, xv, acc[3][u]);
        }
    }
    // KV phase: KV[m][c] += sum_j ks[m][j] * V[c][j]; reduce the 4 pg-lanes, 1 atomic per (m,c)
    for (int m = 0; m < MDIM; ++m) {
        float p0 = 0, p1 = 0, p2 = 0, p3 = 0;
        #pragma unroll
        for (int u = 0; u < 16; ++u) {
            float kv = ks[m][pg * 16 + u];
            p0 = fmaf(kv, acc[0][u], p0);
            p1 = fmaf(kv, acc[1][u], p1);
            p2 = fmaf(kv, acc[2][u], p2);
            p3 = fmaf(kv, acc[3][u], p3);
        }
        p0 += __shfl_xor(p0, 1); p0 += __shfl_xor(p0, 2);
        p1 += __shfl_xor(p1, 1); p1 += __shfl_xor(p1, 2);
        p2 += __shfl_xor(p2, 1); p2 += __shfl_xor(p2, 2);
        p3 += __shfl_xor(p3, 1); p3 += __shfl_xor(p3, 2);
        if (pg == 0) {
            float* kvp = KV + (size_t)(b * MDIM + m) * CH + cg * 4;
            atomicAdd(kvp + 0, p0); atomicAdd(kvp + 1, p1);
            atomicAdd(kvp + 2, p2); atomicAdd(kvp + 3, p3);
        }
    }
}

// Gram: energy[b][r][c] = sum_n x[r,n]*x[c,n].  128x128 tile, 8x8 micro, split-K(8).
// LDS stored transposed [k][col] so both operand reads are near-conflict-free.
__global__ __launch_bounds__(256, 2) void k_energy(const float* __restrict__ x,
                                                   float* __restrict__ energy)
{
    __shared__ float xr[32][136];
    __shared__ float xc[32][136];
    const int rt = blockIdx.x >> 1, ct = blockIdx.x & 1;
    const int b = blockIdx.z;
    const int nb = blockIdx.y * 2048;
    const int tid = threadIdx.x;
    const int ty = tid >> 4, tx = tid & 15;
    const int r0 = rt * 128, c0 = ct * 128;
    const float* xb = x + (size_t)b * CH * NPIX;

    float acc[8][8];
    #pragma unroll
    for (int i = 0; i < 8; ++i)
        #pragma unroll
        for (int j = 0; j < 8; ++j) acc[i][j] = 0.f;

    for (int kk = 0; kk < 2048; kk += 32) {
        __syncthreads();
        #pragma unroll
        for (int s = 0; s < 4; ++s) {
            int f4 = tid + s * 256;           // 0..1023
            int row = f4 >> 3, k4 = f4 & 7;
            float4 a = *(const float4*)(xb + (size_t)(r0 + row) * NPIX + nb + kk + k4 * 4);
            xr[k4 * 4 + 0][row] = a.x; xr[k4 * 4 + 1][row] = a.y;
            xr[k4 * 4 + 2][row] = a.z; xr[k4 * 4 + 3][row] = a.w;
            float4 c = *(const float4*)(xb + (size_t)(c0 + row) * NPIX + nb + kk + k4 * 4);
            xc[k4 * 4 + 0][row] = c.x; xc[k4 * 4 + 1][row] = c.y;
            xc[k4 * 4 + 2][row] = c.z; xc[k4 * 4 + 3][row] = c.w;
        }
        __syncthreads();
        for (int k = 0; k < 32; ++k) {
            float4 a0 = *(const float4*)&xr[k][ty * 8];
            float4 a1 = *(const float4*)&xr[k][ty * 8 + 4];
            float4 b0 = *(const float4*)&xc[k][tx * 8];
            float4 b1 = *(const float4*)&xc[k][tx * 8 + 4];
            float av[8] = {a0.x, a0.y, a0.z, a0.w, a1.x, a1.y, a1.z, a1.w};
            float bv[8] = {b0.x, b0.y, b0.z, b0.w, b1.x, b1.y, b1.z, b1.w};
            #pragma unroll
            for (int i = 0; i < 8; ++i)
                #pragma unroll
                for (int j = 0; j < 8; ++j)
                    acc[i][j] = fmaf(av[i], bv[j], acc[i][j]);
        }
    }
    #pragma unroll
    for (int i = 0; i < 8; ++i)
        #pragma unroll
        for (int j = 0; j < 8; ++j)
            atomicAdd(&energy[((size_t)(b * CH) + r0 + ty * 8 + i) * CH + c0 + tx * 8 + j],
                      acc[i][j]);
}

// softmax(max-e) == softmin(e): attn[c][d] = exp(min_d' e - e[c][d]) / sum.
// one block per (b,c) row; writes attn transposed for coalesced final-pass reads.
__global__ void k_softmax(const float* __restrict__ energy, float* __restrict__ attnT) {
    const int b = blockIdx.x >> 8, c = blockIdx.x & 255;
    const int d = threadIdx.x;
    __shared__ float red[8];
    float e = energy[((size_t)(b * CH) + c) * CH + d];
    float mn = e;
    #pragma unroll
    for (int o = 1; o < 64; o <<= 1) mn = fminf(mn, __shfl_xor(mn, o));
    if ((d & 63) == 0) red[d >> 6] = mn;
    __syncthreads();
    mn = fminf(fminf(red[0], red[1]), fminf(red[2], red[3]));
    float w = expf(mn - e);
    float s = w;
    #pragma unroll
    for (int o = 1; o < 64; o <<= 1) s += __shfl_xor(s, o);
    if ((d & 63) == 0) red[4 + (d >> 6)] = s;
    __syncthreads();
    s = red[4] + red[5] + red[6] + red[7];
    attnT[((size_t)(b * CH) + d) * CH + c] = w / s;
}

// out = x + gk * (sum_m Q[m,n]*KV[m,c]) / (sum_m Q[m,n]*(Ksum[m]+eps)) + gc * sum_d attn[c,d]*x[d,n]
__global__ __launch_bounds__(256, 2) void k_final(
    const float* __restrict__ x, const float* __restrict__ Q,
    const float* __restrict__ KV, const float* __restrict__ Ksum,
    const float* __restrict__ attnT, const float* __restrict__ gk,
    const float* __restrict__ gc, float* __restrict__ out)
{
    __shared__ float xs[CH][64];
    __shared__ float qs[MDIM][64];
    const int b = blockIdx.y, n0 = blockIdx.x * 64, tid = threadIdx.x;
    const float* xb = x + (size_t)b * CH * NPIX;

    #pragma unroll
    for (int s = 0; s < 16; ++s) {
        int e4 = tid + s * 256;
        int c = e4 >> 4, j4 = e4 & 15;
        *(float4*)&xs[c][j4 * 4] = *(const float4*)(xb + (size_t)c * NPIX + n0 + j4 * 4);
    }
    #pragma unroll
    for (int s = 0; s < 2; ++s) {
        int e4 = tid + s * 256;
        int m = e4 >> 4, j4 = e4 & 15;
        *(float4*)&qs[m][j4 * 4] =
            *(const float4*)(Q + (size_t)(b * MDIM + m) * NPIX + n0 + j4 * 4);
    }
    __syncthreads();

    const int cg = tid >> 2, pg = tid & 3;
    const float gkv = gk[0], gcv = gc[0];
    float acc[4][16];
    float den[16];
    #pragma unroll
    for (int u = 0; u < 16; ++u) den[u] = 0.f;
    #pragma unroll
    for (int i = 0; i < 4; ++i)
        #pragma unroll
        for (int u = 0; u < 16; ++u) acc[i][u] = 0.f;

    for (int m = 0; m < MDIM; ++m) {
        float4 kv4 = *(const float4*)(KV + (size_t)(b * MDIM + m) * CH + cg * 4);
        float ksm = Ksum[b * MDIM + m] + EPSF;
        #pragma unroll
        for (int u = 0; u < 16; ++u) {
            float qv = qs[m][pg * 16 + u];
            acc[0][u] = fmaf(kv4.x, qv, acc[0][u]);
            acc[1][u] = fmaf(kv4.y, qv, acc[1][u]);
            acc[2][u] = fmaf(kv4.z, qv, acc[2][u]);
            acc[3][u] = fmaf(kv4.w, qv, acc[3][u]);
            den[u] = fmaf(ksm, qv, den[u]);
        }
    }
    #pragma unroll
    for (int u = 0; u < 16; ++u) den[u] = gkv / den[u];
    #pragma unroll
    for (int i = 0; i < 4; ++i)
        #pragma unroll
        for (int u = 0; u < 16; ++u)
            acc[i][u] = fmaf(acc[i][u], den[u], xs[cg * 4 + i][pg * 16 + u]);

    for (int d = 0; d < CH; ++d) {
        float4 a4 = *(const float4*)(attnT + ((size_t)(b * CH) + d) * CH + cg * 4);
        a4.x *= gcv; a4.y *= gcv; a4.z *= gcv; a4.w *= gcv;
        #pragma unroll
        for (int u = 0; u < 16; ++u) {
            float xv = xs[d][pg * 16 + u];
            acc[0][u] = fmaf(a4.x, xv, acc[0][u]);
            acc[1][u] = fmaf(a4.y, xv, acc[1][u]);
            acc[2][u] = fmaf(a4.z, xv, acc[2][u]);
            acc[3][u] = fmaf(a4.w, xv, acc[3][u]);
        }
    }
    #pragma unroll
    for (int i = 0; i < 4; ++i) {
        float* op = out + ((size_t)(b * CH) + cg * 4 + i) * NPIX + n0 + pg * 16;
        #pragma unroll
        for (int u4 = 0; u4 < 4; ++u4) {
            float4 v = make_float4(acc[i][u4 * 4 + 0], acc[i][u4 * 4 + 1],
                                   acc[i][u4 * 4 + 2], acc[i][u4 * 4 + 3]);
            *(float4*)(op + u4 * 4) = v;
        }
    }
}

extern "C" void kernel_launch(void* const* d_in, const int* in_sizes, int n_in,
                              void* d_out, int out_size, void* d_ws, size_t ws_size,
                              hipStream_t stream)
{
    const float* x  = (const float*)d_in[0];
    const float* wq = (const float*)d_in[1];
    const float* bq = (const float*)d_in[2];
    const float* wk = (const float*)d_in[3];
    const float* bk = (const float*)d_in[4];
    const float* wv = (const float*)d_in[5];
    const float* bv = (const float*)d_in[6];
    const float* gk = (const float*)d_in[7];
    const float* gc = (const float*)d_in[8];
    float* out = (float*)d_out;
    float* ws = (float*)d_ws;

    float* Q    = ws + OFF_Q;
    float* KV   = ws + OFF_KV;
    float* Ksum = ws + OFF_KSUM;
    float* EN   = ws + OFF_EN;
    float* ATT  = ws + OFF_ATT;
    float* WVT  = ws + OFF_WVT;

    hipMemsetAsync(KV, 0, (65536 + 256) * sizeof(float), stream);   // KV + Ksum
    hipMemsetAsync(EN, 0, 524288 * sizeof(float), stream);          // energy

    k_transpose<<<dim3(CH), dim3(CH), 0, stream>>>(wv, WVT);
    k_qkv<<<dim3(NPIX / 64, NB), dim3(256), 0, stream>>>(x, wq, bq, wk, bk, WVT, bv,
                                                         Q, KV, Ksum);
    k_energy<<<dim3(4, 8, NB), dim3(256), 0, stream>>>(x, EN);
    k_softmax<<<dim3(NB * CH), dim3(CH), 0, stream>>>(EN, ATT);
    k_final<<<dim3(NPIX / 64, NB), dim3(256), 0, stream>>>(x, Q, KV, Ksum, ATT, gk, gc, out);
}

// Round 2
// 1078.966 us; speedup vs baseline: 1.3695x; 1.3695x over previous
//
#include <hip/hip_runtime.h>
#include <math.h>

#define NPIX 16384
#define CH 256
#define MDIM 32
#define NB 8
#define EPSF 1e-6f
#define SPLIT 8
#define KCH (NPIX / SPLIT)   // 2048

// ws layout (float offsets) — ~19.4 MB total
#define OFF_Q    0ull          // [B][M][N]  8*32*16384 = 4194304
#define OFF_KV   4194304ull    // [B][M][C]  65536
#define OFF_KSUM 4259840ull    // [B][M]     256
#define OFF_ATT  4260096ull    // [B][C(d)][C(c)] transposed attn, 524288
#define OFF_WVT  4784384ull    // [C(in)][C(out)] 65536

// d_out doubles as scratch before k_final overwrites it (stream-ordered):
//   [0, 16777216)            kvpart [B][T=256][M][C]
//   [16777216, 20971520)     enpart [SPLIT][B][C][C]
#define KVPART_SZ 16777216ull

typedef short short8 __attribute__((ext_vector_type(8)));
typedef float f32x4 __attribute__((ext_vector_type(4)));

__device__ inline unsigned short f2bf(float v) {
    unsigned u = __builtin_bit_cast(unsigned, v);
    unsigned r = u + 0x7FFFu + ((u >> 16) & 1u);   // RNE (finite inputs)
    return (unsigned short)(r >> 16);
}
__device__ inline float bf2f(unsigned short h) {
    unsigned u = (unsigned)h << 16;
    return __builtin_bit_cast(float, u);
}

__global__ void k_transpose(const float* __restrict__ wv, float* __restrict__ wvT) {
    int o = blockIdx.x, d = threadIdx.x;
    wvT[d * CH + o] = wv[o * CH + d];
}

// Fused Q/K (softplus) conv + V conv + KV partial per block (NO global atomics
// for KV anymore: coalesced float4 stores to kvpart, reduced by k_kvreduce).
__global__ __launch_bounds__(256, 2) void k_qkv(
    const float* __restrict__ x,
    const float* __restrict__ wq, const float* __restrict__ bq,
    const float* __restrict__ wk, const float* __restrict__ bk,
    const float* __restrict__ wvT, const float* __restrict__ bv,
    float* __restrict__ Q, float* __restrict__ kvpart, float* __restrict__ Ksum)
{
    __shared__ float xs[CH][64];
    __shared__ float ks[MDIM][64];
    const int b = blockIdx.y;
    const int t = blockIdx.x;          // n-tile
    const int n0 = t * 64;
    const int tid = threadIdx.x;
    const float* xb = x + (size_t)b * CH * NPIX;

    #pragma unroll
    for (int s = 0; s < 16; ++s) {
        int e4 = tid + s * 256;
        int c = e4 >> 4, j4 = e4 & 15;
        float4 v = *(const float4*)(xb + (size_t)c * NPIX + n0 + j4 * 4);
        *(float4*)&xs[c][j4 * 4] = v;
    }
    __syncthreads();

    {   // Q/K phase: wave w handles m = w*8..w*8+7, lane = pixel j
        const int j = tid & 63, mg = tid >> 6;
        float qa[8], ka[8];
        #pragma unroll
        for (int i = 0; i < 8; ++i) { qa[i] = bq[mg * 8 + i]; ka[i] = bk[mg * 8 + i]; }
        for (int d = 0; d < CH; ++d) {
            float xv = xs[d][j];
            #pragma unroll
            for (int i = 0; i < 8; ++i) {
                qa[i] = fmaf(wq[(mg * 8 + i) * CH + d], xv, qa[i]);
                ka[i] = fmaf(wk[(mg * 8 + i) * CH + d], xv, ka[i]);
            }
        }
        #pragma unroll
        for (int i = 0; i < 8; ++i) {
            int m = mg * 8 + i;
            float qv = qa[i], kv = ka[i];
            qv = fmaxf(qv, 0.f) + log1pf(expf(-fabsf(qv)));  // softplus
            kv = fmaxf(kv, 0.f) + log1pf(expf(-fabsf(kv)));
            Q[(size_t)(b * MDIM + m) * NPIX + n0 + j] = qv;
            ks[m][j] = kv;
        }
    }
    __syncthreads();

    if (tid < MDIM) {  // Ksum partial for this pixel tile (tiny atomic traffic)
        float s = 0.f;
        #pragma unroll
        for (int j = 0; j < 64; ++j) s += ks[tid][j];
        atomicAdd(&Ksum[b * MDIM + tid], s);
    }

    // V phase: thread -> 4 out-channels (cg) x 16 pixels (pg)
    const int cg = tid >> 2, pg = tid & 3;
    float acc[4][16];
    #pragma unroll
    for (int i = 0; i < 4; ++i) {
        float bvv = bv[cg * 4 + i];
        #pragma unroll
        for (int u = 0; u < 16; ++u) acc[i][u] = bvv;
    }
    for (int d = 0; d < CH; ++d) {
        float4 w4 = *(const float4*)(wvT + d * CH + cg * 4);
        #pragma unroll
        for (int u = 0; u < 16; ++u) {
            float xv = xs[d][pg * 16 + u];
            acc[0][u] = fmaf(w4.x, xv, acc[0][u]);
            acc[1][u] = fmaf(w4.y, xv, acc[1][u]);
            acc[2][u] = fmaf(w4.z, xv, acc[2][u]);
            acc[3][u] = fmaf(w4.w, xv, acc[3][u]);
        }
    }
    // KV partial: KV[m][c] += sum_j ks[m][j] * V[c][j]; shfl-reduce 4 pg lanes,
    // pg==0 stores one float4 per (m, cg) — coalesced, no atomics.
    for (int m = 0; m < MDIM; ++m) {
        float p0 = 0, p1 = 0, p2 = 0, p3 = 0;
        #pragma unroll
        for (int u = 0; u < 16; ++u) {
            float kv = ks[m][pg * 16 + u];
            p0 = fmaf(kv, acc[0][u], p0);
            p1 = fmaf(kv, acc[1][u], p1);
            p2 = fmaf(kv, acc[2][u], p2);
            p3 = fmaf(kv, acc[3][u], p3);
        }
        p0 += __shfl_xor(p0, 1); p0 += __shfl_xor(p0, 2);
        p1 += __shfl_xor(p1, 1); p1 += __shfl_xor(p1, 2);
        p2 += __shfl_xor(p2, 1); p2 += __shfl_xor(p2, 2);
        p3 += __shfl_xor(p3, 1); p3 += __shfl_xor(p3, 2);
        if (pg == 0) {
            float* kvp = kvpart + (((size_t)b * 256 + t) * MDIM + m) * CH + cg * 4;
            *(float4*)kvp = make_float4(p0, p1, p2, p3);
        }
    }
}

// KV[b][m][c] = sum_t kvpart[b][t][m][c]; block per (b,m), thread per c.
__global__ void k_kvreduce(const float* __restrict__ kvpart, float* __restrict__ KV) {
    const int b = blockIdx.x >> 5, m = blockIdx.x & 31, c = threadIdx.x;
    float s = 0.f;
    #pragma unroll 4
    for (int t = 0; t < 256; ++t)
        s += kvpart[(((size_t)b * 256 + t) * MDIM + m) * CH + c];
    KV[((size_t)b * MDIM + m) * CH + c] = s;
}

// Gram via split-bf16 MFMA: E = Xh·Xh^T + Xh·Xl^T + Xl·Xh^T (ll term ~2^-18, dropped).
// 128x128 tile/block, 4 waves (2x2) of 64x64, K-chunk 2048, fills of K=64.
// LDS rows padded to 72 bf16 (144B): b128 frag reads spread uniformly over banks.
__global__ __launch_bounds__(256, 2) void k_gram(const float* __restrict__ x,
                                                 float* __restrict__ enpart)
{
    __shared__ unsigned short lds[4 * 128 * 72];   // Ah, Al, Bh, Bl = 72 KiB
    unsigned short* Ah = lds;
    unsigned short* Al = lds + 128 * 72;
    unsigned short* Bh = lds + 2 * 128 * 72;
    unsigned short* Bl = lds + 3 * 128 * 72;

    const int tid = threadIdx.x;
    const int rt = blockIdx.x >> 1, ct = blockIdx.x & 1;
    const int sp = blockIdx.y, b = blockIdx.z;
    const int r0 = rt * 128, c0 = ct * 128;
    const float* xb = x + (size_t)b * CH * NPIX;
    const int k0base = sp * KCH;

    const int wave = tid >> 6, lane = tid & 63;
    const int wr = wave >> 1, wc = wave & 1;

    f32x4 acc[4][4];
    #pragma unroll
    for (int i = 0; i < 4; ++i)
        #pragma unroll
        for (int j = 0; j < 4; ++j)
            acc[i][j] = (f32x4){0.f, 0.f, 0.f, 0.f};

    const int oct = tid & 7;      // 8 consecutive k (16B)
    const int frow = tid >> 3;    // 0..31

    for (int kk = 0; kk < KCH; kk += 64) {
        __syncthreads();
        const int k0 = k0base + kk;
        #pragma unroll
        for (int half = 0; half < 2; ++half) {
            const int rowbase = half ? c0 : r0;
            unsigned short* Hh = half ? Bh : Ah;
            unsigned short* Hl = half ? Bl : Al;
            #pragma unroll
            for (int s = 0; s < 4; ++s) {
                const int r = frow + s * 32;
                const float* src = xb + (size_t)(rowbase + r) * NPIX + k0 + oct * 8;
                float4 v0 = *(const float4*)src;
                float4 v1 = *(const float4*)(src + 4);
                float vv[8] = {v0.x, v0.y, v0.z, v0.w, v1.x, v1.y, v1.z, v1.w};
                short8 ph, pl;
                #pragma unroll
                for (int e = 0; e < 8; ++e) {
                    unsigned short h = f2bf(vv[e]);
                    unsigned short l = f2bf(vv[e] - bf2f(h));
                    ph[e] = (short)h;
                    pl[e] = (short)l;
                }
                *(short8*)&Hh[r * 72 + oct * 8] = ph;
                *(short8*)&Hl[r * 72 + oct * 8] = pl;
            }
        }
        __syncthreads();

        #pragma unroll
        for (int ks2 = 0; ks2 < 2; ++ks2) {
            short8 ah[4], al[4], bh[4], bl[4];
            const int rbase = wr * 64 + (lane & 15);
            const int cbase = wc * 64 + (lane & 15);
            const int koff = ks2 * 32 + (lane >> 4) * 8;
            #pragma unroll
            for (int f = 0; f < 4; ++f) {
                ah[f] = *(const short8*)&Ah[(rbase + f * 16) * 72 + koff];
                al[f] = *(const short8*)&Al[(rbase + f * 16) * 72 + koff];
                bh[f] = *(const short8*)&Bh[(cbase + f * 16) * 72 + koff];
                bl[f] = *(const short8*)&Bl[(cbase + f * 16) * 72 + koff];
            }
            #pragma unroll
            for (int i = 0; i < 4; ++i)
                #pragma unroll
                for (int j = 0; j < 4; ++j) {
                    acc[i][j] = __builtin_amdgcn_mfma_f32_16x16x32_bf16(ah[i], bh[j], acc[i][j], 0, 0, 0);
                    acc[i][j] = __builtin_amdgcn_mfma_f32_16x16x32_bf16(ah[i], bl[j], acc[i][j], 0, 0, 0);
                    acc[i][j] = __builtin_amdgcn_mfma_f32_16x16x32_bf16(al[i], bh[j], acc[i][j], 0, 0, 0);
                }
        }
    }

    // C/D layout (HW-verified): col = lane&15, row = (lane>>4)*4 + reg
    float* ep = enpart + (size_t)(sp * NB + b) * (CH * CH);
    const int rw = (lane >> 4) * 4;
    const int cw = lane & 15;
    #pragma unroll
    for (int i = 0; i < 4; ++i)
        #pragma unroll
        for (int j = 0; j < 4; ++j) {
            const int row = r0 + wr * 64 + i * 16 + rw;
            const int col = c0 + wc * 64 + j * 16 + cw;
            #pragma unroll
            for (int q = 0; q < 4; ++q)
                ep[(size_t)(row + q) * CH + col] = acc[i][j][q];
        }
}

// softmax(max-e) == softmin(e); sums the SPLIT partials first.
__global__ void k_softmax(const float* __restrict__ enpart, float* __restrict__ attnT) {
    const int b = blockIdx.x >> 8, c = blockIdx.x & 255;
    const int d = threadIdx.x;
    __shared__ float red[8];
    float e = 0.f;
    #pragma unroll
    for (int sp = 0; sp < SPLIT; ++sp)
        e += enpart[(size_t)(sp * NB + b) * (CH * CH) + (size_t)c * CH + d];
    float mn = e;
    #pragma unroll
    for (int o = 1; o < 64; o <<= 1) mn = fminf(mn, __shfl_xor(mn, o));
    if ((d & 63) == 0) red[d >> 6] = mn;
    __syncthreads();
    mn = fminf(fminf(red[0], red[1]), fminf(red[2], red[3]));
    float w = expf(mn - e);
    float s = w;
    #pragma unroll
    for (int o = 1; o < 64; o <<= 1) s += __shfl_xor(s, o);
    if ((d & 63) == 0) red[4 + (d >> 6)] = s;
    __syncthreads();
    s = red[4] + red[5] + red[6] + red[7];
    attnT[((size_t)(b * CH) + d) * CH + c] = w / s;
}

// out = x + gk*(Q·KV)/(Q·(Ksum+eps)) + gc*(attn·x)
__global__ __launch_bounds__(256, 2) void k_final(
    const float* __restrict__ x, const float* __restrict__ Q,
    const float* __restrict__ KV, const float* __restrict__ Ksum,
    const float* __restrict__ attnT, const float* __restrict__ gk,
    const float* __restrict__ gc, float* __restrict__ out)
{
    __shared__ float xs[CH][64];
    __shared__ float qs[MDIM][64];
    const int b = blockIdx.y, n0 = blockIdx.x * 64, tid = threadIdx.x;
    const float* xb = x + (size_t)b * CH * NPIX;

    #pragma unroll
    for (int s = 0; s < 16; ++s) {
        int e4 = tid + s * 256;
        int c = e4 >> 4, j4 = e4 & 15;
        *(float4*)&xs[c][j4 * 4] = *(const float4*)(xb + (size_t)c * NPIX + n0 + j4 * 4);
    }
    #pragma unroll
    for (int s = 0; s < 2; ++s) {
        int e4 = tid + s * 256;
        int m = e4 >> 4, j4 = e4 & 15;
        *(float4*)&qs[m][j4 * 4] =
            *(const float4*)(Q + (size_t)(b * MDIM + m) * NPIX + n0 + j4 * 4);
    }
    __syncthreads();

    const int cg = tid >> 2, pg = tid & 3;
    const float gkv = gk[0], gcv = gc[0];
    float acc[4][16];
    float den[16];
    #pragma unroll
    for (int u = 0; u < 16; ++u) den[u] = 0.f;
    #pragma unroll
    for (int i = 0; i < 4; ++i)
        #pragma unroll
        for (int u = 0; u < 16; ++u) acc[i][u] = 0.f;

    for (int m = 0; m < MDIM; ++m) {
        float4 kv4 = *(const float4*)(KV + (size_t)(b * MDIM + m) * CH + cg * 4);
        float ksm = Ksum[b * MDIM + m] + EPSF;
        #pragma unroll
        for (int u = 0; u < 16; ++u) {
            float qv = qs[m][pg * 16 + u];
            acc[0][u] = fmaf(kv4.x, qv, acc[0][u]);
            acc[1][u] = fmaf(kv4.y, qv, acc[1][u]);
            acc[2][u] = fmaf(kv4.z, qv, acc[2][u]);
            acc[3][u] = fmaf(kv4.w, qv, acc[3][u]);
            den[u] = fmaf(ksm, qv, den[u]);
        }
    }
    #pragma unroll
    for (int u = 0; u < 16; ++u) den[u] = gkv / den[u];
    #pragma unroll
    for (int i = 0; i < 4; ++i)
        #pragma unroll
        for (int u = 0; u < 16; ++u)
            acc[i][u] = fmaf(acc[i][u], den[u], xs[cg * 4 + i][pg * 16 + u]);

    for (int d = 0; d < CH; ++d) {
        float4 a4 = *(const float4*)(attnT + ((size_t)(b * CH) + d) * CH + cg * 4);
        a4.x *= gcv; a4.y *= gcv; a4.z *= gcv; a4.w *= gcv;
        #pragma unroll
        for (int u = 0; u < 16; ++u) {
            float xv = xs[d][pg * 16 + u];
            acc[0][u] = fmaf(a4.x, xv, acc[0][u]);
            acc[1][u] = fmaf(a4.y, xv, acc[1][u]);
            acc[2][u] = fmaf(a4.z, xv, acc[2][u]);
            acc[3][u] = fmaf(a4.w, xv, acc[3][u]);
        }
    }
    #pragma unroll
    for (int i = 0; i < 4; ++i) {
        float* op = out + ((size_t)(b * CH) + cg * 4 + i) * NPIX + n0 + pg * 16;
        #pragma unroll
        for (int u4 = 0; u4 < 4; ++u4) {
            float4 v = make_float4(acc[i][u4 * 4 + 0], acc[i][u4 * 4 + 1],
                                   acc[i][u4 * 4 + 2], acc[i][u4 * 4 + 3]);
            *(float4*)(op + u4 * 4) = v;
        }
    }
}

extern "C" void kernel_launch(void* const* d_in, const int* in_sizes, int n_in,
                              void* d_out, int out_size, void* d_ws, size_t ws_size,
                              hipStream_t stream)
{
    const float* x  = (const float*)d_in[0];
    const float* wq = (const float*)d_in[1];
    const float* bq = (const float*)d_in[2];
    const float* wk = (const float*)d_in[3];
    const float* bk = (const float*)d_in[4];
    const float* wv = (const float*)d_in[5];
    const float* bv = (const float*)d_in[6];
    const float* gk = (const float*)d_in[7];
    const float* gc = (const float*)d_in[8];
    float* out = (float*)d_out;
    float* ws = (float*)d_ws;

    float* Q    = ws + OFF_Q;
    float* KV   = ws + OFF_KV;
    float* Ksum = ws + OFF_KSUM;
    float* ATT  = ws + OFF_ATT;
    float* WVT  = ws + OFF_WVT;

    float* kvpart = out;                 // d_out as scratch (overwritten by k_final)
    float* enpart = out + KVPART_SZ;

    hipMemsetAsync(Ksum, 0, 256 * sizeof(float), stream);

    k_transpose<<<dim3(CH), dim3(CH), 0, stream>>>(wv, WVT);
    k_qkv<<<dim3(NPIX / 64, NB), dim3(256), 0, stream>>>(x, wq, bq, wk, bk, WVT, bv,
                                                         Q, kvpart, Ksum);
    k_kvreduce<<<dim3(NB * MDIM), dim3(CH), 0, stream>>>(kvpart, KV);
    k_gram<<<dim3(4, SPLIT, NB), dim3(256), 0, stream>>>(x, enpart);
    k_softmax<<<dim3(NB * CH), dim3(CH), 0, stream>>>(enpart, ATT);
    k_final<<<dim3(NPIX / 64, NB), dim3(256), 0, stream>>>(x, Q, KV, Ksum, ATT, gk, gc, out);
}

// Round 3
// 620.402 us; speedup vs baseline: 2.3817x; 1.7391x over previous
//
#include <hip/hip_runtime.h>
#include <math.h>

#define NPIX 16384
#define CH 256
#define MDIM 32
#define NB 8
#define EPSF 1e-6f
#define SPLIT 8
#define KCH (NPIX / SPLIT)   // 2048

// ws layout (float offsets) — ~19.4 MB total
#define OFF_Q    0ull          // [B][M][N]  8*32*16384 = 4194304
#define OFF_KV   4194304ull    // [B][M][C]  65536
#define OFF_KSUM 4259840ull    // [B][M]     256
#define OFF_ATT  4260096ull    // [B][C(d)][C(c)] transposed attn, 524288
#define OFF_XKR  4784384ull    // [B][M][C(d)]  65536

// d_out doubles as scratch before k_final overwrites it (stream-ordered):
//   [0, 16777216)            xkpart [B][T=256][M][D=256]
//   [16777216, 20971520)     enpart [SPLIT][B][C][C]
#define XKPART_SZ 16777216ull

typedef short short8 __attribute__((ext_vector_type(8)));
typedef float f32x4 __attribute__((ext_vector_type(4)));

__device__ inline unsigned short f2bf(float v) {
    unsigned u = __builtin_bit_cast(unsigned, v);
    unsigned r = u + 0x7FFFu + ((u >> 16) & 1u);   // RNE (finite inputs)
    return (unsigned short)(r >> 16);
}
__device__ inline float bf2f(unsigned short h) {
    unsigned u = (unsigned)h << 16;
    return __builtin_bit_cast(float, u);
}

// Fused Q/K (softplus) conv + XK partial:  XK[d][m] = sum_n x[d,n]*K[m,n].
// V-conv algebraically eliminated: KV = wv·XK + bv⊗Ksum (see k_kv).
// LDS 44.5 KB -> 3 blocks/CU (12 waves/CU).
__global__ __launch_bounds__(256, 3) void k_qkx(
    const float* __restrict__ x,
    const float* __restrict__ wq, const float* __restrict__ bq,
    const float* __restrict__ wk, const float* __restrict__ bk,
    float* __restrict__ Q, float* __restrict__ xkpart, float* __restrict__ Ksum)
{
    __shared__ unsigned short xs[CH][72];   // bf16 x tile, 144B row (16B-aligned, bank-spread)
    __shared__ float ks[MDIM][68];          // fp32 softplus(K) tile
    const int b = blockIdx.y, t = blockIdx.x, n0 = t * 64, tid = threadIdx.x;
    const float* xb = x + (size_t)b * CH * NPIX;

    // stage x tile as bf16: 2048 groups of 8 px, 8 per thread
    #pragma unroll
    for (int s = 0; s < 8; ++s) {
        int e8 = tid + s * 256;
        int c = e8 >> 3, j8 = e8 & 7;
        const float* src = xb + (size_t)c * NPIX + n0 + j8 * 8;
        float4 v0 = *(const float4*)src;
        float4 v1 = *(const float4*)(src + 4);
        float vv[8] = {v0.x, v0.y, v0.z, v0.w, v1.x, v1.y, v1.z, v1.w};
        short8 p;
        #pragma unroll
        for (int e = 0; e < 8; ++e) p[e] = (short)f2bf(vv[e]);
        *(short8*)&xs[c][j8 * 8] = p;
    }
    __syncthreads();

    {   // QK phase: wave mg handles m = mg*8..mg*8+7, lane = pixel j
        const int j = tid & 63;
        const int mg = __builtin_amdgcn_readfirstlane(tid >> 6);  // wave-uniform -> s_load weights
        float qa[8], ka[8];
        #pragma unroll
        for (int i = 0; i < 8; ++i) { qa[i] = bq[mg * 8 + i]; ka[i] = bk[mg * 8 + i]; }
        #pragma unroll 4
        for (int d = 0; d < CH; ++d) {
            float xv = bf2f(xs[d][j]);
            #pragma unroll
            for (int i = 0; i < 8; ++i) {
                qa[i] = fmaf(wq[(mg * 8 + i) * CH + d], xv, qa[i]);
                ka[i] = fmaf(wk[(mg * 8 + i) * CH + d], xv, ka[i]);
            }
        }
        #pragma unroll
        for (int i = 0; i < 8; ++i) {
            int m = mg * 8 + i;
            float qv = qa[i], kv = ka[i];
            qv = fmaxf(qv, 0.f) + log1pf(expf(-fabsf(qv)));  // softplus
            kv = fmaxf(kv, 0.f) + log1pf(expf(-fabsf(kv)));
            Q[(size_t)(b * MDIM + m) * NPIX + n0 + j] = qv;
            ks[m][j] = kv;
        }
    }
    __syncthreads();

    if (tid < MDIM) {  // Ksum partial (no eps; eps applied in k_final)
        float s = 0.f;
        #pragma unroll
        for (int j = 0; j < 64; ++j) s += ks[tid][j];
        atomicAdd(&Ksum[b * MDIM + tid], s);
    }

    // XK phase: thread -> 4 x-channels (cg) x 16 pixels (pg)
    const int cg = tid >> 2, pg = tid & 3;
    float xv[4][16];
    #pragma unroll
    for (int i = 0; i < 4; ++i) {
        short8 a0 = *(const short8*)&xs[cg * 4 + i][pg * 16];
        short8 a1 = *(const short8*)&xs[cg * 4 + i][pg * 16 + 8];
        #pragma unroll
        for (int e = 0; e < 8; ++e) {
            xv[i][e]     = bf2f((unsigned short)a0[e]);
            xv[i][8 + e] = bf2f((unsigned short)a1[e]);
        }
    }
    for (int m = 0; m < MDIM; ++m) {
        float4 k0 = *(const float4*)&ks[m][pg * 16];       // same-addr per pg -> broadcast
        float4 k1 = *(const float4*)&ks[m][pg * 16 + 4];
        float4 k2 = *(const float4*)&ks[m][pg * 16 + 8];
        float4 k3 = *(const float4*)&ks[m][pg * 16 + 12];
        float kk[16] = {k0.x, k0.y, k0.z, k0.w, k1.x, k1.y, k1.z, k1.w,
                        k2.x, k2.y, k2.z, k2.w, k3.x, k3.y, k3.z, k3.w};
        float p0 = 0, p1 = 0, p2 = 0, p3 = 0;
        #pragma unroll
        for (int u = 0; u < 16; ++u) {
            p0 = fmaf(kk[u], xv[0][u], p0);
            p1 = fmaf(kk[u], xv[1][u], p1);
            p2 = fmaf(kk[u], xv[2][u], p2);
            p3 = fmaf(kk[u], xv[3][u], p3);
        }
        p0 += __shfl_xor(p0, 1); p0 += __shfl_xor(p0, 2);
        p1 += __shfl_xor(p1, 1); p1 += __shfl_xor(p1, 2);
        p2 += __shfl_xor(p2, 1); p2 += __shfl_xor(p2, 2);
        p3 += __shfl_xor(p3, 1); p3 += __shfl_xor(p3, 2);
        if (pg == 0) {
            float* xp = xkpart + (((size_t)b * 256 + t) * MDIM + m) * CH + cg * 4;
            *(float4*)xp = make_float4(p0, p1, p2, p3);
        }
    }
}

// XKR[b][m][d] = sum_t xkpart[b][t][m][d]
__global__ void k_xkreduce(const float* __restrict__ xkpart, float* __restrict__ XKR) {
    const int b = blockIdx.x >> 5, m = blockIdx.x & 31, d = threadIdx.x;
    float s = 0.f;
    #pragma unroll 4
    for (int t = 0; t < 256; ++t)
        s += xkpart[(((size_t)b * 256 + t) * MDIM + m) * CH + d];
    XKR[((size_t)b * MDIM + m) * CH + d] = s;
}

// KV[m][c] = sum_d wv[c][d]*XKR[m][d] + bv[c]*Ksum[m]
__global__ void k_kv(const float* __restrict__ wv, const float* __restrict__ bv,
                     const float* __restrict__ XKR, const float* __restrict__ Ksum,
                     float* __restrict__ KV) {
    const int b = blockIdx.x, q = blockIdx.y;
    const int ci = threadIdx.x & 63, mg = threadIdx.x >> 6;
    const int c = q * 64 + ci;
    float s[8];
    const float bvc = bv[c];
    #pragma unroll
    for (int i = 0; i < 8; ++i) s[i] = bvc * Ksum[b * MDIM + mg * 8 + i];
    #pragma unroll 4
    for (int d = 0; d < CH; ++d) {
        float w = wv[(size_t)c * CH + d];
        #pragma unroll
        for (int i = 0; i < 8; ++i)
            s[i] = fmaf(w, XKR[((size_t)b * MDIM + mg * 8 + i) * CH + d], s[i]);
    }
    #pragma unroll
    for (int i = 0; i < 8; ++i)
        KV[((size_t)b * MDIM + mg * 8 + i) * CH + c] = s[i];
}

// Gram via split-bf16 MFMA, SYMMETRY-AWARE: E symmetric -> compute tile-blocks
// (0,0),(0,1),(1,1) only; off-diag writes both triangles; diag stages one tile.
__global__ __launch_bounds__(256, 2) void k_gram(const float* __restrict__ x,
                                                 float* __restrict__ enpart)
{
    __shared__ unsigned short lds[4 * 128 * 72];   // Ah, Al, Bh, Bl = 72 KiB
    unsigned short* Ah = lds;
    unsigned short* Al = lds + 128 * 72;
    unsigned short* Bh = lds + 2 * 128 * 72;
    unsigned short* Bl = lds + 3 * 128 * 72;

    const int tid = threadIdx.x;
    const int rt = (blockIdx.x == 2) ? 1 : 0;
    const int ct = (blockIdx.x == 0) ? 0 : 1;
    const bool diag = (rt == ct);
    const int sp = blockIdx.y, b = blockIdx.z;
    const int r0 = rt * 128, c0 = ct * 128;
    const float* xb = x + (size_t)b * CH * NPIX;
    const int k0base = sp * KCH;

    unsigned short* Bh_p = diag ? Ah : Bh;
    unsigned short* Bl_p = diag ? Al : Bl;

    const int wave = tid >> 6, lane = tid & 63;
    const int wr = wave >> 1, wc = wave & 1;

    f32x4 acc[4][4];
    #pragma unroll
    for (int i = 0; i < 4; ++i)
        #pragma unroll
        for (int j = 0; j < 4; ++j)
            acc[i][j] = (f32x4){0.f, 0.f, 0.f, 0.f};

    const int oct = tid & 7;
    const int frow = tid >> 3;

    for (int kk = 0; kk < KCH; kk += 64) {
        __syncthreads();
        const int k0 = k0base + kk;
        #pragma unroll
        for (int half = 0; half < 2; ++half) {
            if (half && diag) continue;
            const int rowbase = half ? c0 : r0;
            unsigned short* Hh = half ? Bh : Ah;
            unsigned short* Hl = half ? Bl : Al;
            #pragma unroll
            for (int s = 0; s < 4; ++s) {
                const int r = frow + s * 32;
                const float* src = xb + (size_t)(rowbase + r) * NPIX + k0 + oct * 8;
                float4 v0 = *(const float4*)src;
                float4 v1 = *(const float4*)(src + 4);
                float vv[8] = {v0.x, v0.y, v0.z, v0.w, v1.x, v1.y, v1.z, v1.w};
                short8 ph, pl;
                #pragma unroll
                for (int e = 0; e < 8; ++e) {
                    unsigned short h = f2bf(vv[e]);
                    unsigned short l = f2bf(vv[e] - bf2f(h));
                    ph[e] = (short)h;
                    pl[e] = (short)l;
                }
                *(short8*)&Hh[r * 72 + oct * 8] = ph;
                *(short8*)&Hl[r * 72 + oct * 8] = pl;
            }
        }
        __syncthreads();

        #pragma unroll
        for (int ks2 = 0; ks2 < 2; ++ks2) {
            short8 ah[4], al[4], bh[4], bl[4];
            const int rbase = wr * 64 + (lane & 15);
            const int cbase = wc * 64 + (lane & 15);
            const int koff = ks2 * 32 + (lane >> 4) * 8;
            #pragma unroll
            for (int f = 0; f < 4; ++f) {
                ah[f] = *(const short8*)&Ah[(rbase + f * 16) * 72 + koff];
                al[f] = *(const short8*)&Al[(rbase + f * 16) * 72 + koff];
                bh[f] = *(const short8*)&Bh_p[(cbase + f * 16) * 72 + koff];
                bl[f] = *(const short8*)&Bl_p[(cbase + f * 16) * 72 + koff];
            }
            #pragma unroll
            for (int i = 0; i < 4; ++i)
                #pragma unroll
                for (int j = 0; j < 4; ++j) {
                    acc[i][j] = __builtin_amdgcn_mfma_f32_16x16x32_bf16(ah[i], bh[j], acc[i][j], 0, 0, 0);
                    acc[i][j] = __builtin_amdgcn_mfma_f32_16x16x32_bf16(ah[i], bl[j], acc[i][j], 0, 0, 0);
                    acc[i][j] = __builtin_amdgcn_mfma_f32_16x16x32_bf16(al[i], bh[j], acc[i][j], 0, 0, 0);
                }
        }
    }

    // C/D layout: col = lane&15, row = (lane>>4)*4 + reg
    float* ep = enpart + (size_t)(sp * NB + b) * (CH * CH);
    const int rw = (lane >> 4) * 4;
    const int cw = lane & 15;
    #pragma unroll
    for (int i = 0; i < 4; ++i)
        #pragma unroll
        for (int j = 0; j < 4; ++j) {
            const int row = r0 + wr * 64 + i * 16 + rw;
            const int col = c0 + wc * 64 + j * 16 + cw;
            #pragma unroll
            for (int q = 0; q < 4; ++q) {
                float v = acc[i][j][q];
                ep[(size_t)(row + q) * CH + col] = v;
                if (!diag) ep[(size_t)col * CH + (row + q)] = v;   // symmetric mirror
            }
        }
}

// softmax(max-e) == softmin(e); sums the SPLIT partials first.
__global__ void k_softmax(const float* __restrict__ enpart, float* __restrict__ attnT) {
    const int b = blockIdx.x >> 8, c = blockIdx.x & 255;
    const int d = threadIdx.x;
    __shared__ float red[8];
    float e = 0.f;
    #pragma unroll
    for (int sp = 0; sp < SPLIT; ++sp)
        e += enpart[(size_t)(sp * NB + b) * (CH * CH) + (size_t)c * CH + d];
    float mn = e;
    #pragma unroll
    for (int o = 1; o < 64; o <<= 1) mn = fminf(mn, __shfl_xor(mn, o));
    if ((d & 63) == 0) red[d >> 6] = mn;
    __syncthreads();
    mn = fminf(fminf(red[0], red[1]), fminf(red[2], red[3]));
    float w = expf(mn - e);
    float s = w;
    #pragma unroll
    for (int o = 1; o < 64; o <<= 1) s += __shfl_xor(s, o);
    if ((d & 63) == 0) red[4 + (d >> 6)] = s;
    __syncthreads();
    s = red[4] + red[5] + red[6] + red[7];
    attnT[((size_t)(b * CH) + d) * CH + c] = w / s;
}

// out = x + gk*(Q·KV)/(Q·(Ksum+eps)) + gc*(attn·x)
__global__ __launch_bounds__(256, 2) void k_final(
    const float* __restrict__ x, const float* __restrict__ Q,
    const float* __restrict__ KV, const float* __restrict__ Ksum,
    const float* __restrict__ attnT, const float* __restrict__ gk,
    const float* __restrict__ gc, float* __restrict__ out)
{
    __shared__ float xs[CH][64];
    __shared__ float qs[MDIM][64];
    const int b = blockIdx.y, n0 = blockIdx.x * 64, tid = threadIdx.x;
    const float* xb = x + (size_t)b * CH * NPIX;

    #pragma unroll
    for (int s = 0; s < 16; ++s) {
        int e4 = tid + s * 256;
        int c = e4 >> 4, j4 = e4 & 15;
        *(float4*)&xs[c][j4 * 4] = *(const float4*)(xb + (size_t)c * NPIX + n0 + j4 * 4);
    }
    #pragma unroll
    for (int s = 0; s < 2; ++s) {
        int e4 = tid + s * 256;
        int m = e4 >> 4, j4 = e4 & 15;
        *(float4*)&qs[m][j4 * 4] =
            *(const float4*)(Q + (size_t)(b * MDIM + m) * NPIX + n0 + j4 * 4);
    }
    __syncthreads();

    const int cg = tid >> 2, pg = tid & 3;
    const float gkv = gk[0], gcv = gc[0];
    float acc[4][16];
    float den[16];
    #pragma unroll
    for (int u = 0; u < 16; ++u) den[u] = 0.f;
    #pragma unroll
    for (int i = 0; i < 4; ++i)
        #pragma unroll
        for (int u = 0; u < 16; ++u) acc[i][u] = 0.f;

    for (int m = 0; m < MDIM; ++m) {
        float4 kv4 = *(const float4*)(KV + (size_t)(b * MDIM + m) * CH + cg * 4);
        float ksm = Ksum[b * MDIM + m] + EPSF;
        #pragma unroll
        for (int u = 0; u < 16; ++u) {
            float qv = qs[m][pg * 16 + u];
            acc[0][u] = fmaf(kv4.x, qv, acc[0][u]);
            acc[1][u] = fmaf(kv4.y, qv, acc[1][u]);
            acc[2][u] = fmaf(kv4.z, qv, acc[2][u]);
            acc[3][u] = fmaf(kv4.w, qv, acc[3][u]);
            den[u] = fmaf(ksm, qv, den[u]);
        }
    }
    #pragma unroll
    for (int u = 0; u < 16; ++u) den[u] = gkv / den[u];
    #pragma unroll
    for (int i = 0; i < 4; ++i)
        #pragma unroll
        for (int u = 0; u < 16; ++u)
            acc[i][u] = fmaf(acc[i][u], den[u], xs[cg * 4 + i][pg * 16 + u]);

    for (int d = 0; d < CH; ++d) {
        float4 a4 = *(const float4*)(attnT + ((size_t)(b * CH) + d) * CH + cg * 4);
        a4.x *= gcv; a4.y *= gcv; a4.z *= gcv; a4.w *= gcv;
        #pragma unroll
        for (int u = 0; u < 16; ++u) {
            float xv = xs[d][pg * 16 + u];
            acc[0][u] = fmaf(a4.x, xv, acc[0][u]);
            acc[1][u] = fmaf(a4.y, xv, acc[1][u]);
            acc[2][u] = fmaf(a4.z, xv, acc[2][u]);
            acc[3][u] = fmaf(a4.w, xv, acc[3][u]);
        }
    }
    #pragma unroll
    for (int i = 0; i < 4; ++i) {
        float* op = out + ((size_t)(b * CH) + cg * 4 + i) * NPIX + n0 + pg * 16;
        #pragma unroll
        for (int u4 = 0; u4 < 4; ++u4) {
            float4 v = make_float4(acc[i][u4 * 4 + 0], acc[i][u4 * 4 + 1],
                                   acc[i][u4 * 4 + 2], acc[i][u4 * 4 + 3]);
            *(float4*)(op + u4 * 4) = v;
        }
    }
}

extern "C" void kernel_launch(void* const* d_in, const int* in_sizes, int n_in,
                              void* d_out, int out_size, void* d_ws, size_t ws_size,
                              hipStream_t stream)
{
    const float* x  = (const float*)d_in[0];
    const float* wq = (const float*)d_in[1];
    const float* bq = (const float*)d_in[2];
    const float* wk = (const float*)d_in[3];
    const float* bk = (const float*)d_in[4];
    const float* wv = (const float*)d_in[5];
    const float* bv = (const float*)d_in[6];
    const float* gk = (const float*)d_in[7];
    const float* gc = (const float*)d_in[8];
    float* out = (float*)d_out;
    float* ws = (float*)d_ws;

    float* Q    = ws + OFF_Q;
    float* KV   = ws + OFF_KV;
    float* Ksum = ws + OFF_KSUM;
    float* ATT  = ws + OFF_ATT;
    float* XKR  = ws + OFF_XKR;

    float* xkpart = out;                 // d_out as scratch (overwritten by k_final)
    float* enpart = out + XKPART_SZ;

    hipMemsetAsync(Ksum, 0, 256 * sizeof(float), stream);

    k_qkx<<<dim3(NPIX / 64, NB), dim3(256), 0, stream>>>(x, wq, bq, wk, bk, Q, xkpart, Ksum);
    k_xkreduce<<<dim3(NB * MDIM), dim3(CH), 0, stream>>>(xkpart, XKR);
    k_kv<<<dim3(NB, 4), dim3(256), 0, stream>>>(wv, bv, XKR, Ksum, KV);
    k_gram<<<dim3(3, SPLIT, NB), dim3(256), 0, stream>>>(x, enpart);
    k_softmax<<<dim3(NB * CH), dim3(CH), 0, stream>>>(enpart, ATT);
    k_final<<<dim3(NPIX / 64, NB), dim3(256), 0, stream>>>(x, Q, KV, Ksum, ATT, gk, gc, out);
}

// Round 4
// 393.389 us; speedup vs baseline: 3.7562x; 1.5771x over previous
//
#include <hip/hip_runtime.h>
#include <math.h>

#define NPIX 16384
#define CH 256
#define MDIM 32
#define NB 8
#define EPSF 1e-6f
#define SPLIT 8
#define KCH (NPIX / SPLIT)   // 2048

// ws BYTE layout
//   QTB  @ 0        : bf16 Q^T [B][N][M]   8,388,608 B
//   ATTB @ 8388608  : bf16 attn [B][C][D]  1,048,576 B
//   KVTB @ 9437184  : bf16 KV^T [B][C][M]    131,072 B
//   KSUM @ 9568256  : f32 [B][M]               1,024 B
//   XKR  @ 9569280  : f32 [B][M][D]          262,144 B
// d_out doubles as scratch before k_final overwrites it (stream-ordered):
//   [0, 16777216)  floats        xkpart [B][T=256][M][D=256]
//   [16777216, 20971520) floats  enpart [SPLIT][B][C][C]
#define XKPART_SZ 16777216ull

typedef short short8 __attribute__((ext_vector_type(8)));
typedef float f32x4 __attribute__((ext_vector_type(4)));

__device__ inline unsigned short f2bf(float v) {
    unsigned u = __builtin_bit_cast(unsigned, v);
    unsigned r = u + 0x7FFFu + ((u >> 16) & 1u);   // RNE (finite inputs)
    return (unsigned short)(r >> 16);
}
__device__ inline float bf2f(unsigned short h) {
    unsigned u = (unsigned)h << 16;
    return __builtin_bit_cast(float, u);
}

// Fused Q/K (softplus) conv + XK partial.  Writes Q^T as bf16 (lane j holds
// 8 consecutive m == one MFMA B-fragment -> single 16B store).
__global__ __launch_bounds__(256, 3) void k_qkx(
    const float* __restrict__ x,
    const float* __restrict__ wq, const float* __restrict__ bq,
    const float* __restrict__ wk, const float* __restrict__ bk,
    unsigned short* __restrict__ Qtb, float* __restrict__ xkpart,
    float* __restrict__ Ksum)
{
    __shared__ unsigned short xs[CH][72];   // bf16 x tile
    __shared__ float ks[MDIM][68];          // fp32 softplus(K) tile
    const int b = blockIdx.y, t = blockIdx.x, n0 = t * 64, tid = threadIdx.x;
    const float* xb = x + (size_t)b * CH * NPIX;

    #pragma unroll
    for (int s = 0; s < 8; ++s) {
        int e8 = tid + s * 256;
        int c = e8 >> 3, j8 = e8 & 7;
        const float* src = xb + (size_t)c * NPIX + n0 + j8 * 8;
        float4 v0 = *(const float4*)src;
        float4 v1 = *(const float4*)(src + 4);
        float vv[8] = {v0.x, v0.y, v0.z, v0.w, v1.x, v1.y, v1.z, v1.w};
        short8 p;
        #pragma unroll
        for (int e = 0; e < 8; ++e) p[e] = (short)f2bf(vv[e]);
        *(short8*)&xs[c][j8 * 8] = p;
    }
    __syncthreads();

    {   // QK phase: wave mg handles m = mg*8..mg*8+7, lane = pixel j
        const int j = tid & 63;
        const int mg = __builtin_amdgcn_readfirstlane(tid >> 6);
        float qa[8], ka[8];
        #pragma unroll
        for (int i = 0; i < 8; ++i) { qa[i] = bq[mg * 8 + i]; ka[i] = bk[mg * 8 + i]; }
        #pragma unroll 4
        for (int d = 0; d < CH; ++d) {
            float xv = bf2f(xs[d][j]);
            #pragma unroll
            for (int i = 0; i < 8; ++i) {
                qa[i] = fmaf(wq[(mg * 8 + i) * CH + d], xv, qa[i]);
                ka[i] = fmaf(wk[(mg * 8 + i) * CH + d], xv, ka[i]);
            }
        }
        short8 q8;
        #pragma unroll
        for (int i = 0; i < 8; ++i) {
            int m = mg * 8 + i;
            float qv = qa[i], kv = ka[i];
            qv = fmaxf(qv, 0.f) + log1pf(expf(-fabsf(qv)));  // softplus
            kv = fmaxf(kv, 0.f) + log1pf(expf(-fabsf(kv)));
            q8[i] = (short)f2bf(qv);
            ks[m][j] = kv;
        }
        *(short8*)(Qtb + ((size_t)b * NPIX + n0 + j) * MDIM + mg * 8) = q8;
    }
    __syncthreads();

    if (tid < MDIM) {
        float s = 0.f;
        #pragma unroll
        for (int j = 0; j < 64; ++j) s += ks[tid][j];
        atomicAdd(&Ksum[b * MDIM + tid], s);
    }

    // XK phase: thread -> 4 x-channels (cg) x 16 pixels (pg)
    const int cg = tid >> 2, pg = tid & 3;
    float xv[4][16];
    #pragma unroll
    for (int i = 0; i < 4; ++i) {
        short8 a0 = *(const short8*)&xs[cg * 4 + i][pg * 16];
        short8 a1 = *(const short8*)&xs[cg * 4 + i][pg * 16 + 8];
        #pragma unroll
        for (int e = 0; e < 8; ++e) {
            xv[i][e]     = bf2f((unsigned short)a0[e]);
            xv[i][8 + e] = bf2f((unsigned short)a1[e]);
        }
    }
    for (int m = 0; m < MDIM; ++m) {
        float4 k0 = *(const float4*)&ks[m][pg * 16];
        float4 k1 = *(const float4*)&ks[m][pg * 16 + 4];
        float4 k2 = *(const float4*)&ks[m][pg * 16 + 8];
        float4 k3 = *(const float4*)&ks[m][pg * 16 + 12];
        float kk[16] = {k0.x, k0.y, k0.z, k0.w, k1.x, k1.y, k1.z, k1.w,
                        k2.x, k2.y, k2.z, k2.w, k3.x, k3.y, k3.z, k3.w};
        float p0 = 0, p1 = 0, p2 = 0, p3 = 0;
        #pragma unroll
        for (int u = 0; u < 16; ++u) {
            p0 = fmaf(kk[u], xv[0][u], p0);
            p1 = fmaf(kk[u], xv[1][u], p1);
            p2 = fmaf(kk[u], xv[2][u], p2);
            p3 = fmaf(kk[u], xv[3][u], p3);
        }
        p0 += __shfl_xor(p0, 1); p0 += __shfl_xor(p0, 2);
        p1 += __shfl_xor(p1, 1); p1 += __shfl_xor(p1, 2);
        p2 += __shfl_xor(p2, 1); p2 += __shfl_xor(p2, 2);
        p3 += __shfl_xor(p3, 1); p3 += __shfl_xor(p3, 2);
        if (pg == 0) {
            float* xp = xkpart + (((size_t)b * 256 + t) * MDIM + m) * CH + cg * 4;
            *(float4*)xp = make_float4(p0, p1, p2, p3);
        }
    }
}

__global__ void k_xkreduce(const float* __restrict__ xkpart, float* __restrict__ XKR) {
    const int b = blockIdx.x >> 5, m = blockIdx.x & 31, d = threadIdx.x;
    float s = 0.f;
    #pragma unroll 4
    for (int t = 0; t < 256; ++t)
        s += xkpart[(((size_t)b * 256 + t) * MDIM + m) * CH + d];
    XKR[((size_t)b * MDIM + m) * CH + d] = s;
}

// KV^T[c][m] (bf16) = sum_d wv[c][d]*XKR[m][d] + bv[c]*Ksum[m]
__global__ void k_kv(const float* __restrict__ wv, const float* __restrict__ bv,
                     const float* __restrict__ XKR, const float* __restrict__ Ksum,
                     unsigned short* __restrict__ KVTb) {
    const int b = blockIdx.x, q = blockIdx.y;
    const int ci = threadIdx.x & 63, mg = threadIdx.x >> 6;
    const int c = q * 64 + ci;
    float s[8];
    const float bvc = bv[c];
    #pragma unroll
    for (int i = 0; i < 8; ++i) s[i] = bvc * Ksum[b * MDIM + mg * 8 + i];
    #pragma unroll 4
    for (int d = 0; d < CH; ++d) {
        float w = wv[(size_t)c * CH + d];
        #pragma unroll
        for (int i = 0; i < 8; ++i)
            s[i] = fmaf(w, XKR[((size_t)b * MDIM + mg * 8 + i) * CH + d], s[i]);
    }
    short8 p;
    #pragma unroll
    for (int i = 0; i < 8; ++i) p[i] = (short)f2bf(s[i]);
    *(short8*)(KVTb + ((size_t)b * CH + c) * MDIM + mg * 8) = p;
}

// Gram via split-bf16 MFMA, symmetry-aware (unchanged from round 2/3).
__global__ __launch_bounds__(256, 2) void k_gram(const float* __restrict__ x,
                                                 float* __restrict__ enpart)
{
    __shared__ unsigned short lds[4 * 128 * 72];
    unsigned short* Ah = lds;
    unsigned short* Al = lds + 128 * 72;
    unsigned short* Bh = lds + 2 * 128 * 72;
    unsigned short* Bl = lds + 3 * 128 * 72;

    const int tid = threadIdx.x;
    const int rt = (blockIdx.x == 2) ? 1 : 0;
    const int ct = (blockIdx.x == 0) ? 0 : 1;
    const bool diag = (rt == ct);
    const int sp = blockIdx.y, b = blockIdx.z;
    const int r0 = rt * 128, c0 = ct * 128;
    const float* xb = x + (size_t)b * CH * NPIX;
    const int k0base = sp * KCH;

    unsigned short* Bh_p = diag ? Ah : Bh;
    unsigned short* Bl_p = diag ? Al : Bl;

    const int wave = tid >> 6, lane = tid & 63;
    const int wr = wave >> 1, wc = wave & 1;

    f32x4 acc[4][4];
    #pragma unroll
    for (int i = 0; i < 4; ++i)
        #pragma unroll
        for (int j = 0; j < 4; ++j)
            acc[i][j] = (f32x4){0.f, 0.f, 0.f, 0.f};

    const int oct = tid & 7;
    const int frow = tid >> 3;

    for (int kk = 0; kk < KCH; kk += 64) {
        __syncthreads();
        const int k0 = k0base + kk;
        #pragma unroll
        for (int half = 0; half < 2; ++half) {
            if (half && diag) continue;
            const int rowbase = half ? c0 : r0;
            unsigned short* Hh = half ? Bh : Ah;
            unsigned short* Hl = half ? Bl : Al;
            #pragma unroll
            for (int s = 0; s < 4; ++s) {
                const int r = frow + s * 32;
                const float* src = xb + (size_t)(rowbase + r) * NPIX + k0 + oct * 8;
                float4 v0 = *(const float4*)src;
                float4 v1 = *(const float4*)(src + 4);
                float vv[8] = {v0.x, v0.y, v0.z, v0.w, v1.x, v1.y, v1.z, v1.w};
                short8 ph, pl;
                #pragma unroll
                for (int e = 0; e < 8; ++e) {
                    unsigned short h = f2bf(vv[e]);
                    unsigned short l = f2bf(vv[e] - bf2f(h));
                    ph[e] = (short)h;
                    pl[e] = (short)l;
                }
                *(short8*)&Hh[r * 72 + oct * 8] = ph;
                *(short8*)&Hl[r * 72 + oct * 8] = pl;
            }
        }
        __syncthreads();

        #pragma unroll
        for (int ks2 = 0; ks2 < 2; ++ks2) {
            short8 ah[4], al[4], bh[4], bl[4];
            const int rbase = wr * 64 + (lane & 15);
            const int cbase = wc * 64 + (lane & 15);
            const int koff = ks2 * 32 + (lane >> 4) * 8;
            #pragma unroll
            for (int f = 0; f < 4; ++f) {
                ah[f] = *(const short8*)&Ah[(rbase + f * 16) * 72 + koff];
                al[f] = *(const short8*)&Al[(rbase + f * 16) * 72 + koff];
                bh[f] = *(const short8*)&Bh_p[(cbase + f * 16) * 72 + koff];
                bl[f] = *(const short8*)&Bl_p[(cbase + f * 16) * 72 + koff];
            }
            #pragma unroll
            for (int i = 0; i < 4; ++i)
                #pragma unroll
                for (int j = 0; j < 4; ++j) {
                    acc[i][j] = __builtin_amdgcn_mfma_f32_16x16x32_bf16(ah[i], bh[j], acc[i][j], 0, 0, 0);
                    acc[i][j] = __builtin_amdgcn_mfma_f32_16x16x32_bf16(ah[i], bl[j], acc[i][j], 0, 0, 0);
                    acc[i][j] = __builtin_amdgcn_mfma_f32_16x16x32_bf16(al[i], bh[j], acc[i][j], 0, 0, 0);
                }
        }
    }

    float* ep = enpart + (size_t)(sp * NB + b) * (CH * CH);
    const int rw = (lane >> 4) * 4;
    const int cw = lane & 15;
    #pragma unroll
    for (int i = 0; i < 4; ++i)
        #pragma unroll
        for (int j = 0; j < 4; ++j) {
            const int row = r0 + wr * 64 + i * 16 + rw;
            const int col = c0 + wc * 64 + j * 16 + cw;
            #pragma unroll
            for (int q = 0; q < 4; ++q) {
                float v = acc[i][j][q];
                ep[(size_t)(row + q) * CH + col] = v;
                if (!diag) ep[(size_t)col * CH + (row + q)] = v;
            }
        }
}

// softmin over summed partials; emits bf16 attn [b][c][d].
__global__ void k_softmax(const float* __restrict__ enpart,
                          unsigned short* __restrict__ attnb) {
    const int b = blockIdx.x >> 8, c = blockIdx.x & 255;
    const int d = threadIdx.x;
    __shared__ float red[8];
    float e = 0.f;
    #pragma unroll
    for (int sp = 0; sp < SPLIT; ++sp)
        e += enpart[(size_t)(sp * NB + b) * (CH * CH) + (size_t)c * CH + d];
    float mn = e;
    #pragma unroll
    for (int o = 1; o < 64; o <<= 1) mn = fminf(mn, __shfl_xor(mn, o));
    if ((d & 63) == 0) red[d >> 6] = mn;
    __syncthreads();
    mn = fminf(fminf(red[0], red[1]), fminf(red[2], red[3]));
    float w = expf(mn - e);
    float s = w;
    #pragma unroll
    for (int o = 1; o < 64; o <<= 1) s += __shfl_xor(s, o);
    if ((d & 63) == 0) red[4 + (d >> 6)] = s;
    __syncthreads();
    s = red[4] + red[5] + red[6] + red[7];
    attnb[((size_t)(b * CH) + c) * CH + d] = f2bf(w / s);
}

// MFMA epilogue kernel: out = x + gk*norm*(KV^T·Q) + gc*(attn·X).
// Block: 256c x 64n, 4 waves (wave w -> c-range [w*64, w*64+64)).
// x-tile transposed into LDS bf16 via in-register 4x4 shuffle transpose,
// XOR-swizzled so both staging writes and b64 fragment reads are bank-floor.
__global__ __launch_bounds__(256, 2) void k_final(
    const float* __restrict__ x, const unsigned short* __restrict__ Qtb,
    const unsigned short* __restrict__ KVTb, const float* __restrict__ Ksum,
    const unsigned short* __restrict__ attnb, const float* __restrict__ gk,
    const float* __restrict__ gc, float* __restrict__ out)
{
    __shared__ uint2 xsTv[4096];            // 32 KB: bf16 xT [n=64][d=256] swizzled
    __shared__ float den_s[64];
    unsigned char* xsT = (unsigned char*)xsTv;
    const int b = blockIdx.y, n0 = blockIdx.x * 64, tid = threadIdx.x;
    const int w = tid >> 6, l = tid & 63;
    const int li = l & 15, lg = l >> 4;
    const float* xb = x + (size_t)b * CH * NPIX;

    // ---- stage xT (each wave stages its own 64-d slice over all 64 n) ----
    {
        const int n4 = li * 4;
        const bool o1 = lg & 1, o2 = (lg >> 1) & 1;
        #pragma unroll
        for (int p = 0; p < 16; ++p) {
            const int d0 = w * 64 + p * 4;
            float4 vv = *(const float4*)(xb + (size_t)(d0 + lg) * NPIX + n0 + n4);
            float v0 = vv.x, v1 = vv.y, v2 = vv.z, v3 = vv.w;
            float r1 = __shfl_xor(o1 ? v0 : v1, 16);
            float r2 = __shfl_xor(o1 ? v2 : v3, 16);
            float a0 = o1 ? r1 : v0, a1 = o1 ? v1 : r1;
            float a2 = o1 ? r2 : v2, a3 = o1 ? v3 : r2;
            float r3 = __shfl_xor(o2 ? a0 : a2, 32);
            float r4 = __shfl_xor(o2 ? a1 : a3, 32);
            float b0 = o2 ? r3 : a0, b1 = o2 ? r4 : a1;
            float b2 = o2 ? a2 : r3, b3 = o2 ? a3 : r4;
            const int nl = n4 + lg;
            unsigned lo = (unsigned)f2bf(b0) | ((unsigned)f2bf(b1) << 16);
            unsigned hi = (unsigned)f2bf(b2) | ((unsigned)f2bf(b3) << 16);
            const int off = nl * 512 +
                ((2 * d0) ^ ((nl & 7) << 4) ^ (((nl >> 3) & 1) << 3));
            *(uint2*)(xsT + off) = make_uint2(lo, hi);
        }
    }
    // ---- den = sum_m Q[n,m]*(Ksum[m]+eps);  den_s = gk/den ----
    if (tid < 64) {
        float den = 0.f;
        const unsigned short* qp = Qtb + ((size_t)b * NPIX + n0 + tid) * MDIM;
        #pragma unroll
        for (int g = 0; g < 4; ++g) {
            short8 q8 = *(const short8*)(qp + g * 8);
            #pragma unroll
            for (int e = 0; e < 8; ++e)
                den = fmaf(bf2f((unsigned short)q8[e]),
                           Ksum[b * MDIM + g * 8 + e] + EPSF, den);
        }
        den_s[tid] = gk[0] / den;
    }
    __syncthreads();

    f32x4 acc[4][4], accP[4][4];
    #pragma unroll
    for (int i = 0; i < 4; ++i)
        #pragma unroll
        for (int j = 0; j < 4; ++j) {
            acc[i][j] = (f32x4){0.f, 0.f, 0.f, 0.f};
            accP[i][j] = (f32x4){0.f, 0.f, 0.f, 0.f};
        }

    // ---- KAM: P = KV^T · Q  (single K=32 step) ----
    {
        short8 ka[4], qb[4];
        #pragma unroll
        for (int i = 0; i < 4; ++i)
            ka[i] = *(const short8*)(KVTb +
                ((size_t)b * CH + w * 64 + i * 16 + li) * MDIM + lg * 8);
        #pragma unroll
        for (int j = 0; j < 4; ++j)
            qb[j] = *(const short8*)(Qtb +
                ((size_t)b * NPIX + n0 + j * 16 + li) * MDIM + lg * 8);
        #pragma unroll
        for (int i = 0; i < 4; ++i)
            #pragma unroll
            for (int j = 0; j < 4; ++j)
                accP[i][j] = __builtin_amdgcn_mfma_f32_16x16x32_bf16(ka[i], qb[j], accP[i][j], 0, 0, 0);
    }

    // ---- CAM: attn · X  (8 K=32 steps over d) ----
    const unsigned short* ab = attnb + (size_t)b * CH * CH;
    for (int kk = 0; kk < CH; kk += 32) {
        short8 af[4], bx[4];
        #pragma unroll
        for (int i = 0; i < 4; ++i)
            af[i] = *(const short8*)(ab +
                (size_t)(w * 64 + i * 16 + li) * CH + kk + lg * 8);
        #pragma unroll
        for (int j = 0; j < 4; ++j) {
            const int nf = j * 16 + li;
            const int d2 = 2 * (kk + lg * 8);
            const int sw = ((nf & 7) << 4) ^ (((nf >> 3) & 1) << 3);
            uint2 h0 = *(const uint2*)(xsT + nf * 512 + (d2 ^ sw));
            uint2 h1 = *(const uint2*)(xsT + nf * 512 + ((d2 + 8) ^ sw));
            int4 tmp = make_int4(h0.x, h0.y, h1.x, h1.y);
            bx[j] = __builtin_bit_cast(short8, tmp);
        }
        #pragma unroll
        for (int i = 0; i < 4; ++i)
            #pragma unroll
            for (int j = 0; j < 4; ++j)
                acc[i][j] = __builtin_amdgcn_mfma_f32_16x16x32_bf16(af[i], bx[j], acc[i][j], 0, 0, 0);
    }

    // ---- epilogue: out = x + norm*P + gc*CAM ----
    const float gcv = gc[0];
    #pragma unroll
    for (int i = 0; i < 4; ++i)
        #pragma unroll
        for (int j = 0; j < 4; ++j) {
            const float nrm = den_s[j * 16 + li];
            #pragma unroll
            for (int q = 0; q < 4; ++q) {
                const int c = w * 64 + i * 16 + lg * 4 + q;
                const size_t idx = (size_t)c * NPIX + n0 + j * 16 + li;
                out[(size_t)b * CH * NPIX + idx] =
                    xb[idx] + nrm * accP[i][j][q] + gcv * acc[i][j][q];
            }
        }
}

extern "C" void kernel_launch(void* const* d_in, const int* in_sizes, int n_in,
                              void* d_out, int out_size, void* d_ws, size_t ws_size,
                              hipStream_t stream)
{
    const float* x  = (const float*)d_in[0];
    const float* wq = (const float*)d_in[1];
    const float* bq = (const float*)d_in[2];
    const float* wk = (const float*)d_in[3];
    const float* bk = (const float*)d_in[4];
    const float* wv = (const float*)d_in[5];
    const float* bv = (const float*)d_in[6];
    const float* gk = (const float*)d_in[7];
    const float* gc = (const float*)d_in[8];
    float* out = (float*)d_out;
    char* wsb = (char*)d_ws;

    unsigned short* QTB  = (unsigned short*)(wsb);
    unsigned short* ATTB = (unsigned short*)(wsb + 8388608);
    unsigned short* KVTB = (unsigned short*)(wsb + 9437184);
    float* KSUM = (float*)(wsb + 9568256);
    float* XKR  = (float*)(wsb + 9569280);

    float* xkpart = out;                 // d_out as scratch (overwritten by k_final)
    float* enpart = out + XKPART_SZ;

    hipMemsetAsync(KSUM, 0, 256 * sizeof(float), stream);

    k_qkx<<<dim3(NPIX / 64, NB), dim3(256), 0, stream>>>(x, wq, bq, wk, bk,
                                                         QTB, xkpart, KSUM);
    k_xkreduce<<<dim3(NB * MDIM), dim3(CH), 0, stream>>>(xkpart, XKR);
    k_kv<<<dim3(NB, 4), dim3(256), 0, stream>>>(wv, bv, XKR, KSUM, KVTB);
    k_gram<<<dim3(3, SPLIT, NB), dim3(256), 0, stream>>>(x, enpart);
    k_softmax<<<dim3(NB * CH), dim3(CH), 0, stream>>>(enpart, ATTB);
    k_final<<<dim3(NPIX / 64, NB), dim3(256), 0, stream>>>(x, QTB, KVTB, KSUM,
                                                           ATTB, gk, gc, out);
}

// Round 5
// 354.765 us; speedup vs baseline: 4.1651x; 1.1089x over previous
//
#include <hip/hip_runtime.h>
#include <math.h>

#define NPIX 16384
#define CH 256
#define MDIM 32
#define NB 8
#define EPSF 1e-6f
#define SPLIT 8
#define KCH (NPIX / SPLIT)   // 2048

// ws BYTE layout
//   ATTB @ 0        : bf16 attn [B][C][D]  1,048,576 B
//   KVTB @ 1048576  : bf16 KV^T [B][C][M]    131,072 B
//   KSUM @ 1179648  : f32 [B][M]               1,024 B
//   XKR  @ 1180672  : f32 [B][M][D]          262,144 B
// d_out doubles as scratch before k_final overwrites it (stream-ordered):
//   [0, 16777216)  floats        xkpart [B][T=256][M][D=256]
//   [16777216, 20971520) floats  enpart [SPLIT][B][C][C]
#define XKPART_SZ 16777216ull

typedef short short8 __attribute__((ext_vector_type(8)));
typedef float f32x4 __attribute__((ext_vector_type(4)));

__device__ inline unsigned short f2bf(float v) {
    unsigned u = __builtin_bit_cast(unsigned, v);
    unsigned r = u + 0x7FFFu + ((u >> 16) & 1u);   // RNE (finite inputs)
    return (unsigned short)(r >> 16);
}
__device__ inline float bf2f(unsigned short h) {
    unsigned u = (unsigned)h << 16;
    return __builtin_bit_cast(float, u);
}

// K (softplus) conv on VALU + XK = x·K^T on MFMA.
// xs: bf16 x tile, c-major (n-contiguous rows) with XOR-swizzle so both the
// per-lane broadcast conv reads AND the b128 MFMA A-fragment reads are
// bank-spread.  XK result transposed through LDS so xkpart keeps the
// [b][t][m][d] layout (k_xkreduce/k_kv unchanged).
__global__ __launch_bounds__(256, 3) void k_kx(
    const float* __restrict__ x,
    const float* __restrict__ wk, const float* __restrict__ bk,
    float* __restrict__ xkpart, float* __restrict__ Ksum)
{
    __shared__ unsigned short xs[CH * 80];     // 40 KB bf16, swizzled rows
    __shared__ unsigned short ks[MDIM * 80];   // 5 KB bf16 softplus(K)
    const int b = blockIdx.y, t = blockIdx.x, n0 = t * 64, tid = threadIdx.x;
    const float* xb = x + (size_t)b * CH * NPIX;

    // stage x tile as bf16 (8 px per thread), swizzled 16B granules
    #pragma unroll
    for (int s = 0; s < 8; ++s) {
        int e8 = tid + s * 256;
        int c = e8 >> 3, j8 = e8 & 7;
        const float* src = xb + (size_t)c * NPIX + n0 + j8 * 8;
        float4 v0 = *(const float4*)src;
        float4 v1 = *(const float4*)(src + 4);
        float vv[8] = {v0.x, v0.y, v0.z, v0.w, v1.x, v1.y, v1.z, v1.w};
        short8 p;
        #pragma unroll
        for (int e = 0; e < 8; ++e) p[e] = (short)f2bf(vv[e]);
        *(short8*)&xs[c * 80 + ((j8 * 8) ^ ((c & 7) << 3))] = p;
    }
    __syncthreads();

    {   // K conv: wave mg handles m = mg*8..mg*8+7, lane = pixel j
        const int j = tid & 63;
        const int mg = __builtin_amdgcn_readfirstlane(tid >> 6);
        float ka[8];
        #pragma unroll
        for (int i = 0; i < 8; ++i) ka[i] = bk[mg * 8 + i];
        #pragma unroll 4
        for (int d = 0; d < CH; ++d) {
            float xv = bf2f(xs[d * 80 + (j ^ ((d & 7) << 3))]);
            #pragma unroll
            for (int i = 0; i < 8; ++i)
                ka[i] = fmaf(wk[(mg * 8 + i) * CH + d], xv, ka[i]);
        }
        #pragma unroll
        for (int i = 0; i < 8; ++i) {
            int m = mg * 8 + i;
            float kv = ka[i];
            kv = fmaxf(kv, 0.f) + log1pf(expf(-fabsf(kv)));  // softplus
            ks[m * 80 + (j ^ ((m & 7) << 3))] = f2bf(kv);
        }
    }
    __syncthreads();

    if (tid < MDIM) {   // Ksum partial (bf16-rounded K — consistent with XK)
        float s = 0.f;
        #pragma unroll
        for (int j = 0; j < 64; ++j)
            s += bf2f(ks[tid * 80 + (j ^ ((tid & 7) << 3))]);
        atomicAdd(&Ksum[b * MDIM + tid], s);
    }

    // XK[d][m] = sum_n x[d,n]*K[m,n] via MFMA (wave w -> d-range [w*64, w*64+64))
    const int w = tid >> 6, li = tid & 15, lg = (tid & 63) >> 4;
    f32x4 axk[4][2];
    #pragma unroll
    for (int i = 0; i < 4; ++i)
        #pragma unroll
        for (int j = 0; j < 2; ++j) axk[i][j] = (f32x4){0.f, 0.f, 0.f, 0.f};

    #pragma unroll
    for (int ks2 = 0; ks2 < 2; ++ks2) {
        const int ko = ks2 * 32 + lg * 8;
        short8 kb[2], af[4];
        #pragma unroll
        for (int j = 0; j < 2; ++j) {
            const int m = j * 16 + li;
            kb[j] = *(const short8*)&ks[m * 80 + (ko ^ ((m & 7) << 3))];
        }
        #pragma unroll
        for (int i = 0; i < 4; ++i) {
            const int d = w * 64 + i * 16 + li;
            af[i] = *(const short8*)&xs[d * 80 + (ko ^ ((d & 7) << 3))];
        }
        #pragma unroll
        for (int i = 0; i < 4; ++i)
            #pragma unroll
            for (int j = 0; j < 2; ++j)
                axk[i][j] = __builtin_amdgcn_mfma_f32_16x16x32_bf16(af[i], kb[j], axk[i][j], 0, 0, 0);
    }

    __syncthreads();                 // xs reads done — reuse as f32 buffer
    float* xsF = (float*)xs;         // XK^T staging [m][256 d], XOR d^(m&31)
    #pragma unroll
    for (int i = 0; i < 4; ++i)
        #pragma unroll
        for (int j = 0; j < 2; ++j)
            #pragma unroll
            for (int q = 0; q < 4; ++q) {
                const int d = w * 64 + i * 16 + lg * 4 + q;
                const int m = j * 16 + li;
                xsF[m * 256 + (d ^ (m & 31))] = axk[i][j][q];
            }
    __syncthreads();
    float* xp = xkpart + (size_t)(b * 256 + t) * MDIM * CH;
    #pragma unroll 4
    for (int m = 0; m < MDIM; ++m)
        xp[m * CH + tid] = xsF[m * 256 + (tid ^ (m & 31))];   // conflict-free, coalesced
}

__global__ void k_xkreduce(const float* __restrict__ xkpart, float* __restrict__ XKR) {
    const int b = blockIdx.x >> 5, m = blockIdx.x & 31, d = threadIdx.x;
    float s = 0.f;
    #pragma unroll 4
    for (int t = 0; t < 256; ++t)
        s += xkpart[(((size_t)b * 256 + t) * MDIM + m) * CH + d];
    XKR[((size_t)b * MDIM + m) * CH + d] = s;
}

// KV^T[c][m] (bf16) = sum_d wv[c][d]*XKR[m][d] + bv[c]*Ksum[m]
__global__ void k_kv(const float* __restrict__ wv, const float* __restrict__ bv,
                     const float* __restrict__ XKR, const float* __restrict__ Ksum,
                     unsigned short* __restrict__ KVTb) {
    const int b = blockIdx.x, q = blockIdx.y;
    const int ci = threadIdx.x & 63, mg = threadIdx.x >> 6;
    const int c = q * 64 + ci;
    float s[8];
    const float bvc = bv[c];
    #pragma unroll
    for (int i = 0; i < 8; ++i) s[i] = bvc * Ksum[b * MDIM + mg * 8 + i];
    #pragma unroll 4
    for (int d = 0; d < CH; ++d) {
        float w = wv[(size_t)c * CH + d];
        #pragma unroll
        for (int i = 0; i < 8; ++i)
            s[i] = fmaf(w, XKR[((size_t)b * MDIM + mg * 8 + i) * CH + d], s[i]);
    }
    short8 p;
    #pragma unroll
    for (int i = 0; i < 8; ++i) p[i] = (short)f2bf(s[i]);
    *(short8*)(KVTb + ((size_t)b * CH + c) * MDIM + mg * 8) = p;
}

// Gram via split-bf16 MFMA, symmetry-aware (unchanged).
__global__ __launch_bounds__(256, 2) void k_gram(const float* __restrict__ x,
                                                 float* __restrict__ enpart)
{
    __shared__ unsigned short lds[4 * 128 * 72];
    unsigned short* Ah = lds;
    unsigned short* Al = lds + 128 * 72;
    unsigned short* Bh = lds + 2 * 128 * 72;
    unsigned short* Bl = lds + 3 * 128 * 72;

    const int tid = threadIdx.x;
    const int rt = (blockIdx.x == 2) ? 1 : 0;
    const int ct = (blockIdx.x == 0) ? 0 : 1;
    const bool diag = (rt == ct);
    const int sp = blockIdx.y, b = blockIdx.z;
    const int r0 = rt * 128, c0 = ct * 128;
    const float* xb = x + (size_t)b * CH * NPIX;
    const int k0base = sp * KCH;

    unsigned short* Bh_p = diag ? Ah : Bh;
    unsigned short* Bl_p = diag ? Al : Bl;

    const int wave = tid >> 6, lane = tid & 63;
    const int wr = wave >> 1, wc = wave & 1;

    f32x4 acc[4][4];
    #pragma unroll
    for (int i = 0; i < 4; ++i)
        #pragma unroll
        for (int j = 0; j < 4; ++j)
            acc[i][j] = (f32x4){0.f, 0.f, 0.f, 0.f};

    const int oct = tid & 7;
    const int frow = tid >> 3;

    for (int kk = 0; kk < KCH; kk += 64) {
        __syncthreads();
        const int k0 = k0base + kk;
        #pragma unroll
        for (int half = 0; half < 2; ++half) {
            if (half && diag) continue;
            const int rowbase = half ? c0 : r0;
            unsigned short* Hh = half ? Bh : Ah;
            unsigned short* Hl = half ? Bl : Al;
            #pragma unroll
            for (int s = 0; s < 4; ++s) {
                const int r = frow + s * 32;
                const float* src = xb + (size_t)(rowbase + r) * NPIX + k0 + oct * 8;
                float4 v0 = *(const float4*)src;
                float4 v1 = *(const float4*)(src + 4);
                float vv[8] = {v0.x, v0.y, v0.z, v0.w, v1.x, v1.y, v1.z, v1.w};
                short8 ph, pl;
                #pragma unroll
                for (int e = 0; e < 8; ++e) {
                    unsigned short h = f2bf(vv[e]);
                    unsigned short l = f2bf(vv[e] - bf2f(h));
                    ph[e] = (short)h;
                    pl[e] = (short)l;
                }
                *(short8*)&Hh[r * 72 + oct * 8] = ph;
                *(short8*)&Hl[r * 72 + oct * 8] = pl;
            }
        }
        __syncthreads();

        #pragma unroll
        for (int ks2 = 0; ks2 < 2; ++ks2) {
            short8 ah[4], al[4], bh[4], bl[4];
            const int rbase = wr * 64 + (lane & 15);
            const int cbase = wc * 64 + (lane & 15);
            const int koff = ks2 * 32 + (lane >> 4) * 8;
            #pragma unroll
            for (int f = 0; f < 4; ++f) {
                ah[f] = *(const short8*)&Ah[(rbase + f * 16) * 72 + koff];
                al[f] = *(const short8*)&Al[(rbase + f * 16) * 72 + koff];
                bh[f] = *(const short8*)&Bh_p[(cbase + f * 16) * 72 + koff];
                bl[f] = *(const short8*)&Bl_p[(cbase + f * 16) * 72 + koff];
            }
            #pragma unroll
            for (int i = 0; i < 4; ++i)
                #pragma unroll
                for (int j = 0; j < 4; ++j) {
                    acc[i][j] = __builtin_amdgcn_mfma_f32_16x16x32_bf16(ah[i], bh[j], acc[i][j], 0, 0, 0);
                    acc[i][j] = __builtin_amdgcn_mfma_f32_16x16x32_bf16(ah[i], bl[j], acc[i][j], 0, 0, 0);
                    acc[i][j] = __builtin_amdgcn_mfma_f32_16x16x32_bf16(al[i], bh[j], acc[i][j], 0, 0, 0);
                }
        }
    }

    float* ep = enpart + (size_t)(sp * NB + b) * (CH * CH);
    const int rw = (lane >> 4) * 4;
    const int cw = lane & 15;
    #pragma unroll
    for (int i = 0; i < 4; ++i)
        #pragma unroll
        for (int j = 0; j < 4; ++j) {
            const int row = r0 + wr * 64 + i * 16 + rw;
            const int col = c0 + wc * 64 + j * 16 + cw;
            #pragma unroll
            for (int q = 0; q < 4; ++q) {
                float v = acc[i][j][q];
                ep[(size_t)(row + q) * CH + col] = v;
                if (!diag) ep[(size_t)col * CH + (row + q)] = v;
            }
        }
}

// softmin over summed partials; emits bf16 attn [b][c][d].
__global__ void k_softmax(const float* __restrict__ enpart,
                          unsigned short* __restrict__ attnb) {
    const int b = blockIdx.x >> 8, c = blockIdx.x & 255;
    const int d = threadIdx.x;
    __shared__ float red[8];
    float e = 0.f;
    #pragma unroll
    for (int sp = 0; sp < SPLIT; ++sp)
        e += enpart[(size_t)(sp * NB + b) * (CH * CH) + (size_t)c * CH + d];
    float mn = e;
    #pragma unroll
    for (int o = 1; o < 64; o <<= 1) mn = fminf(mn, __shfl_xor(mn, o));
    if ((d & 63) == 0) red[d >> 6] = mn;
    __syncthreads();
    mn = fminf(fminf(red[0], red[1]), fminf(red[2], red[3]));
    float w = expf(mn - e);
    float s = w;
    #pragma unroll
    for (int o = 1; o < 64; o <<= 1) s += __shfl_xor(s, o);
    if ((d & 63) == 0) red[4 + (d >> 6)] = s;
    __syncthreads();
    s = red[4] + red[5] + red[6] + red[7];
    attnb[((size_t)(b * CH) + c) * CH + d] = f2bf(w / s);
}

// out = x + gk*norm*(KV^T·Q) + gc*(attn·X), with Q computed INLINE via MFMA
// (hi/lo-split bf16 wq × staged xsT).  Block: 256c x 64n, 4 waves.
__global__ __launch_bounds__(256, 2) void k_final(
    const float* __restrict__ x, const float* __restrict__ wq,
    const float* __restrict__ bq,
    const unsigned short* __restrict__ KVTb, const float* __restrict__ Ksum,
    const unsigned short* __restrict__ attnb, const float* __restrict__ gk,
    const float* __restrict__ gc, float* __restrict__ out)
{
    __shared__ uint2 xsTv[4096];            // 32 KB: bf16 xT [n=64][d=256] swizzled
    __shared__ unsigned short qsT[64 * 40]; // 5 KB: bf16 Q [n][m] (pad 40)
    __shared__ float den_s[64];
    unsigned char* xsT = (unsigned char*)xsTv;
    const int b = blockIdx.y, n0 = blockIdx.x * 64, tid = threadIdx.x;
    const int w = tid >> 6, l = tid & 63;
    const int li = l & 15, lg = l >> 4;
    const float* xb = x + (size_t)b * CH * NPIX;

    // ---- stage xT (each wave stages its own 64-d slice over all 64 n) ----
    {
        const int n4 = li * 4;
        const bool o1 = lg & 1, o2 = (lg >> 1) & 1;
        #pragma unroll
        for (int p = 0; p < 16; ++p) {
            const int d0 = w * 64 + p * 4;
            float4 vv = *(const float4*)(xb + (size_t)(d0 + lg) * NPIX + n0 + n4);
            float v0 = vv.x, v1 = vv.y, v2 = vv.z, v3 = vv.w;
            float r1 = __shfl_xor(o1 ? v0 : v1, 16);
            float r2 = __shfl_xor(o1 ? v2 : v3, 16);
            float a0 = o1 ? r1 : v0, a1 = o1 ? v1 : r1;
            float a2 = o1 ? r2 : v2, a3 = o1 ? v3 : r2;
            float r3 = __shfl_xor(o2 ? a0 : a2, 32);
            float r4 = __shfl_xor(o2 ? a1 : a3, 32);
            float b0 = o2 ? r3 : a0, b1 = o2 ? r4 : a1;
            float b2 = o2 ? a2 : r3, b3 = o2 ? a3 : r4;
            const int nl = n4 + lg;
            unsigned lo = (unsigned)f2bf(b0) | ((unsigned)f2bf(b1) << 16);
            unsigned hi = (unsigned)f2bf(b2) | ((unsigned)f2bf(b3) << 16);
            const int off = nl * 512 +
                ((2 * d0) ^ ((nl & 7) << 4) ^ (((nl >> 3) & 1) << 3));
            *(uint2*)(xsT + off) = make_uint2(lo, hi);
        }
    }
    __syncthreads();

    // ---- inline Q: wave w computes Q[m=0..31][n = w*16+li] via MFMA ----
    {
        f32x4 accq[2];
        accq[0] = (f32x4){0.f, 0.f, 0.f, 0.f};
        accq[1] = (f32x4){0.f, 0.f, 0.f, 0.f};
        const int nf = w * 16 + li;
        const int sw = ((nf & 7) << 4) ^ (((nf >> 3) & 1) << 3);
        #pragma unroll
        for (int kc = 0; kc < 8; ++kc) {
            const int d2 = 2 * (kc * 32 + lg * 8);
            uint2 h0 = *(const uint2*)(xsT + nf * 512 + (d2 ^ sw));
            uint2 h1 = *(const uint2*)(xsT + nf * 512 + ((d2 + 8) ^ sw));
            int4 tmp = make_int4(h0.x, h0.y, h1.x, h1.y);
            short8 bxw = __builtin_bit_cast(short8, tmp);
            #pragma unroll
            for (int i = 0; i < 2; ++i) {
                const float* wp = wq + (size_t)(i * 16 + li) * CH + kc * 32 + lg * 8;
                float4 w0 = *(const float4*)wp;
                float4 w1 = *(const float4*)(wp + 4);
                float wv8[8] = {w0.x, w0.y, w0.z, w0.w, w1.x, w1.y, w1.z, w1.w};
                short8 wh, wl;
                #pragma unroll
                for (int e = 0; e < 8; ++e) {
                    unsigned short h = f2bf(wv8[e]);
                    wh[e] = (short)h;
                    wl[e] = (short)f2bf(wv8[e] - bf2f(h));
                }
                accq[i] = __builtin_amdgcn_mfma_f32_16x16x32_bf16(wh, bxw, accq[i], 0, 0, 0);
                accq[i] = __builtin_amdgcn_mfma_f32_16x16x32_bf16(wl, bxw, accq[i], 0, 0, 0);
            }
        }
        float den = 0.f;
        #pragma unroll
        for (int i = 0; i < 2; ++i)
            #pragma unroll
            for (int q = 0; q < 4; ++q) {
                const int m = i * 16 + lg * 4 + q;
                float qv = accq[i][q] + bq[m];
                qv = fmaxf(qv, 0.f) + log1pf(expf(-fabsf(qv)));  // softplus
                qsT[(w * 16 + li) * 40 + m] = f2bf(qv);
                den = fmaf(qv, Ksum[b * MDIM + m] + EPSF, den);
            }
        den += __shfl_xor(den, 16);
        den += __shfl_xor(den, 32);
        if (lg == 0) den_s[w * 16 + li] = gk[0] / den;
    }
    __syncthreads();

    f32x4 acc[4][4], accP[4][4];
    #pragma unroll
    for (int i = 0; i < 4; ++i)
        #pragma unroll
        for (int j = 0; j < 4; ++j) {
            acc[i][j] = (f32x4){0.f, 0.f, 0.f, 0.f};
            accP[i][j] = (f32x4){0.f, 0.f, 0.f, 0.f};
        }

    // ---- KAM: P = KV^T · Q  (single K=32 step) ----
    {
        short8 ka[4], qb[4];
        #pragma unroll
        for (int i = 0; i < 4; ++i)
            ka[i] = *(const short8*)(KVTb +
                ((size_t)b * CH + w * 64 + i * 16 + li) * MDIM + lg * 8);
        #pragma unroll
        for (int j = 0; j < 4; ++j)
            qb[j] = *(const short8*)&qsT[(j * 16 + li) * 40 + lg * 8];
        #pragma unroll
        for (int i = 0; i < 4; ++i)
            #pragma unroll
            for (int j = 0; j < 4; ++j)
                accP[i][j] = __builtin_amdgcn_mfma_f32_16x16x32_bf16(ka[i], qb[j], accP[i][j], 0, 0, 0);
    }

    // ---- CAM: attn · X  (8 K=32 steps over d) ----
    const unsigned short* ab = attnb + (size_t)b * CH * CH;
    for (int kk = 0; kk < CH; kk += 32) {
        short8 af[4], bx[4];
        #pragma unroll
        for (int i = 0; i < 4; ++i)
            af[i] = *(const short8*)(ab +
                (size_t)(w * 64 + i * 16 + li) * CH + kk + lg * 8);
        #pragma unroll
        for (int j = 0; j < 4; ++j) {
            const int nf = j * 16 + li;
            const int d2 = 2 * (kk + lg * 8);
            const int sw = ((nf & 7) << 4) ^ (((nf >> 3) & 1) << 3);
            uint2 h0 = *(const uint2*)(xsT + nf * 512 + (d2 ^ sw));
            uint2 h1 = *(const uint2*)(xsT + nf * 512 + ((d2 + 8) ^ sw));
            int4 tmp = make_int4(h0.x, h0.y, h1.x, h1.y);
            bx[j] = __builtin_bit_cast(short8, tmp);
        }
        #pragma unroll
        for (int i = 0; i < 4; ++i)
            #pragma unroll
            for (int j = 0; j < 4; ++j)
                acc[i][j] = __builtin_amdgcn_mfma_f32_16x16x32_bf16(af[i], bx[j], acc[i][j], 0, 0, 0);
    }

    // ---- epilogue: out = x + norm*P + gc*CAM ----
    const float gcv = gc[0];
    #pragma unroll
    for (int i = 0; i < 4; ++i)
        #pragma unroll
        for (int j = 0; j < 4; ++j) {
            const float nrm = den_s[j * 16 + li];
            #pragma unroll
            for (int q = 0; q < 4; ++q) {
                const int c = w * 64 + i * 16 + lg * 4 + q;
                const size_t idx = (size_t)c * NPIX + n0 + j * 16 + li;
                out[(size_t)b * CH * NPIX + idx] =
                    xb[idx] + nrm * accP[i][j][q] + gcv * acc[i][j][q];
            }
        }
}

extern "C" void kernel_launch(void* const* d_in, const int* in_sizes, int n_in,
                              void* d_out, int out_size, void* d_ws, size_t ws_size,
                              hipStream_t stream)
{
    const float* x  = (const float*)d_in[0];
    const float* wq = (const float*)d_in[1];
    const float* bq = (const float*)d_in[2];
    const float* wk = (const float*)d_in[3];
    const float* bk = (const float*)d_in[4];
    const float* wv = (const float*)d_in[5];
    const float* bv = (const float*)d_in[6];
    const float* gk = (const float*)d_in[7];
    const float* gc = (const float*)d_in[8];
    float* out = (float*)d_out;
    char* wsb = (char*)d_ws;

    unsigned short* ATTB = (unsigned short*)(wsb);
    unsigned short* KVTB = (unsigned short*)(wsb + 1048576);
    float* KSUM = (float*)(wsb + 1179648);
    float* XKR  = (float*)(wsb + 1180672);

    float* xkpart = out;                 // d_out as scratch (overwritten by k_final)
    float* enpart = out + XKPART_SZ;

    hipMemsetAsync(KSUM, 0, 256 * sizeof(float), stream);

    k_kx<<<dim3(NPIX / 64, NB), dim3(256), 0, stream>>>(x, wk, bk, xkpart, KSUM);
    k_gram<<<dim3(3, SPLIT, NB), dim3(256), 0, stream>>>(x, enpart);
    k_xkreduce<<<dim3(NB * MDIM), dim3(CH), 0, stream>>>(xkpart, XKR);
    k_kv<<<dim3(NB, 4), dim3(256), 0, stream>>>(wv, bv, XKR, KSUM, KVTB);
    k_softmax<<<dim3(NB * CH), dim3(CH), 0, stream>>>(enpart, ATTB);
    k_final<<<dim3(NPIX / 64, NB), dim3(256), 0, stream>>>(x, wq, bq, KVTB, KSUM,
                                                           ATTB, gk, gc, out);
}

// Round 6
// 320.756 us; speedup vs baseline: 4.6067x; 1.1060x over previous
//
#include <hip/hip_runtime.h>
#include <math.h>

#define NPIX 16384
#define CH 256
#define MDIM 32
#define NB 8
#define EPSF 1e-6f
#define SPLIT 16
#define KCH (NPIX / SPLIT)   // 1024

// ws BYTE layout
//   ATTB @ 0        : bf16 attn [B][C][D]  1,048,576 B
//   KVTB @ 1048576  : bf16 KV^T [B][C][M]    131,072 B
//   KSUM @ 1179648  : f32 [B][M]               1,024 B
//   XKR  @ 1180672  : f32 [B][M][D]          262,144 B
//   WQH  @ 1442816  : bf16 [M][C] 16384 B   (hi split of wq)
//   WQL  @ 1459200  : bf16 [M][C] 16384 B
//   WKH  @ 1475584  : bf16 [M][C] 16384 B
//   WKL  @ 1491968  : bf16 [M][C] 16384 B
// d_out doubles as scratch before k_final overwrites it (stream-ordered):
//   [0, 16777216) floats          xkpart [B][T=256][M][D=256]
//   [16777216, 25165824) floats   enpart [SPLIT=16][B][C][C]
#define XKPART_SZ 16777216ull

typedef short short8 __attribute__((ext_vector_type(8)));
typedef float f32x4 __attribute__((ext_vector_type(4)));

__device__ inline unsigned short f2bf(float v) {
    unsigned u = __builtin_bit_cast(unsigned, v);
    unsigned r = u + 0x7FFFu + ((u >> 16) & 1u);   // RNE (finite inputs)
    return (unsigned short)(r >> 16);
}
__device__ inline float bf2f(unsigned short h) {
    unsigned u = (unsigned)h << 16;
    return __builtin_bit_cast(float, u);
}

// Pre-split wq/wk into hi/lo bf16 pairs (removes per-block split math downstream).
__global__ void k_prep(const float* __restrict__ wq, const float* __restrict__ wk,
                       unsigned short* __restrict__ WQH, unsigned short* __restrict__ WQL,
                       unsigned short* __restrict__ WKH, unsigned short* __restrict__ WKL)
{
    int i = blockIdx.x * 256 + threadIdx.x;   // 8192 total
    float q = wq[i], k = wk[i];
    unsigned short qh = f2bf(q);
    WQH[i] = qh; WQL[i] = f2bf(q - bf2f(qh));
    unsigned short kh = f2bf(k);
    WKH[i] = kh; WKL[i] = f2bf(k - bf2f(kh));
}

// K = softplus(wk·x+bk) via MFMA (hi/lo weights × swizzled xT tile — the
// HW-validated k_final Q-block pattern), then XK^T[m][d] = sum_n K[m,n]x[d,n]
// via MFMA with B-fragments converted straight from global (L1/L2-hot).
// LDS 37 KB -> 4 blocks/CU.
__global__ __launch_bounds__(256, 4) void k_kx(
    const float* __restrict__ x,
    const unsigned short* __restrict__ WKH, const unsigned short* __restrict__ WKL,
    const float* __restrict__ bk,
    float* __restrict__ xkpart, float* __restrict__ Ksum)
{
    __shared__ uint2 xsTv[4096];               // 32 KB: bf16 xT [n=64][d=256] swizzled
    __shared__ unsigned short ksm[MDIM * 72];  // 4.5 KB: bf16 softplus(K) [m][n]
    unsigned char* xsT = (unsigned char*)xsTv;
    const int b = blockIdx.y, t = blockIdx.x, n0 = t * 64, tid = threadIdx.x;
    const int w = tid >> 6, l = tid & 63;
    const int li = l & 15, lg = l >> 4;
    const float* xb = x + (size_t)b * CH * NPIX;

    // ---- phase 1: stage xT (wave w stages d-slice [w*64, w*64+64)) ----
    {
        const int n4 = li * 4;
        const bool o1 = lg & 1, o2 = (lg >> 1) & 1;
        #pragma unroll
        for (int p = 0; p < 16; ++p) {
            const int d0 = w * 64 + p * 4;
            float4 vv = *(const float4*)(xb + (size_t)(d0 + lg) * NPIX + n0 + n4);
            float v0 = vv.x, v1 = vv.y, v2 = vv.z, v3 = vv.w;
            float r1 = __shfl_xor(o1 ? v0 : v1, 16);
            float r2 = __shfl_xor(o1 ? v2 : v3, 16);
            float a0 = o1 ? r1 : v0, a1 = o1 ? v1 : r1;
            float a2 = o1 ? r2 : v2, a3 = o1 ? v3 : r2;
            float r3 = __shfl_xor(o2 ? a0 : a2, 32);
            float r4 = __shfl_xor(o2 ? a1 : a3, 32);
            float b0 = o2 ? r3 : a0, b1 = o2 ? r4 : a1;
            float b2 = o2 ? a2 : r3, b3 = o2 ? a3 : r4;
            const int nl = n4 + lg;
            unsigned lo = (unsigned)f2bf(b0) | ((unsigned)f2bf(b1) << 16);
            unsigned hi = (unsigned)f2bf(b2) | ((unsigned)f2bf(b3) << 16);
            const int off = nl * 512 +
                ((2 * d0) ^ ((nl & 7) << 4) ^ (((nl >> 3) & 1) << 3));
            *(uint2*)(xsT + off) = make_uint2(lo, hi);
        }
    }
    __syncthreads();

    // ---- phase 2: K via MFMA; wave w covers n = w*16 + li ----
    {
        f32x4 accq[2];
        accq[0] = (f32x4){0.f, 0.f, 0.f, 0.f};
        accq[1] = (f32x4){0.f, 0.f, 0.f, 0.f};
        const int nf = w * 16 + li;
        const int sw = ((nf & 7) << 4) ^ (((nf >> 3) & 1) << 3);
        #pragma unroll
        for (int kc = 0; kc < 8; ++kc) {
            const int d2 = 2 * (kc * 32 + lg * 8);
            uint2 h0 = *(const uint2*)(xsT + nf * 512 + (d2 ^ sw));
            uint2 h1 = *(const uint2*)(xsT + nf * 512 + ((d2 + 8) ^ sw));
            int4 tmp = make_int4(h0.x, h0.y, h1.x, h1.y);
            short8 bxw = __builtin_bit_cast(short8, tmp);
            #pragma unroll
            for (int i = 0; i < 2; ++i) {
                short8 wh = *(const short8*)(WKH + (size_t)(i * 16 + li) * CH + kc * 32 + lg * 8);
                short8 wl = *(const short8*)(WKL + (size_t)(i * 16 + li) * CH + kc * 32 + lg * 8);
                accq[i] = __builtin_amdgcn_mfma_f32_16x16x32_bf16(wh, bxw, accq[i], 0, 0, 0);
                accq[i] = __builtin_amdgcn_mfma_f32_16x16x32_bf16(wl, bxw, accq[i], 0, 0, 0);
            }
        }
        #pragma unroll
        for (int i = 0; i < 2; ++i)
            #pragma unroll
            for (int q = 0; q < 4; ++q) {
                const int m = i * 16 + lg * 4 + q;
                float kv = accq[i][q] + bk[m];
                kv = fmaxf(kv, 0.f) + log1pf(expf(-fabsf(kv)));  // softplus
                ksm[m * 72 + (nf ^ ((m & 7) << 3))] = f2bf(kv);
            }
    }
    __syncthreads();

    if (tid < MDIM) {   // Ksum partial for this tile
        float s = 0.f;
        #pragma unroll
        for (int j = 0; j < 64; ++j)
            s += bf2f(ksm[tid * 72 + (j ^ ((tid & 7) << 3))]);
        atomicAdd(&Ksum[b * MDIM + tid], s);
    }

    // ---- phase 3: XK^T[m][d] via MFMA; wave w -> d-range [w*64, w*64+64) ----
    f32x4 axk[4][2];
    #pragma unroll
    for (int i = 0; i < 4; ++i)
        #pragma unroll
        for (int j = 0; j < 2; ++j) axk[i][j] = (f32x4){0.f, 0.f, 0.f, 0.f};

    #pragma unroll
    for (int ks2 = 0; ks2 < 2; ++ks2) {
        const int nc = ks2 * 32 + lg * 8;
        short8 kfr[2];
        #pragma unroll
        for (int j = 0; j < 2; ++j) {
            const int m = j * 16 + li;
            kfr[j] = *(const short8*)&ksm[m * 72 + (nc ^ ((m & 7) << 3))];
        }
        #pragma unroll
        for (int i = 0; i < 4; ++i) {
            const int d = w * 64 + i * 16 + li;
            const float* sp = xb + (size_t)d * NPIX + n0 + nc;
            float4 v0 = *(const float4*)sp;
            float4 v1 = *(const float4*)(sp + 4);
            float vv[8] = {v0.x, v0.y, v0.z, v0.w, v1.x, v1.y, v1.z, v1.w};
            short8 xf;
            #pragma unroll
            for (int e = 0; e < 8; ++e) xf[e] = (short)f2bf(vv[e]);
            #pragma unroll
            for (int j = 0; j < 2; ++j)
                axk[i][j] = __builtin_amdgcn_mfma_f32_16x16x32_bf16(kfr[j], xf, axk[i][j], 0, 0, 0);
        }
    }

    __syncthreads();                 // xsT reads all done — reuse as f32 scratch
    float* xsF = (float*)xsTv;       // [32 m][256 d], XOR-swizzled
    #pragma unroll
    for (int i = 0; i < 4; ++i)
        #pragma unroll
        for (int j = 0; j < 2; ++j)
            #pragma unroll
            for (int q = 0; q < 4; ++q) {
                const int m = j * 16 + lg * 4 + q;
                const int d = w * 64 + i * 16 + li;
                xsF[m * 256 + (d ^ ((m & 7) << 2))] = axk[i][j][q];
            }
    __syncthreads();
    float* xp = xkpart + (size_t)(b * 256 + t) * MDIM * CH;
    #pragma unroll 4
    for (int m = 0; m < MDIM; ++m)
        xp[m * CH + tid] = xsF[m * 256 + (tid ^ ((m & 7) << 2))];
}

__global__ void k_xkreduce(const float* __restrict__ xkpart, float* __restrict__ XKR) {
    const int b = blockIdx.x >> 5, m = blockIdx.x & 31, d = threadIdx.x;
    float s = 0.f;
    #pragma unroll 4
    for (int t = 0; t < 256; ++t)
        s += xkpart[(((size_t)b * 256 + t) * MDIM + m) * CH + d];
    XKR[((size_t)b * MDIM + m) * CH + d] = s;
}

// KV^T[c][m] (bf16) = sum_d wv[c][d]*XKR[m][d] + bv[c]*Ksum[m]
__global__ void k_kv(const float* __restrict__ wv, const float* __restrict__ bv,
                     const float* __restrict__ XKR, const float* __restrict__ Ksum,
                     unsigned short* __restrict__ KVTb) {
    const int b = blockIdx.x, q = blockIdx.y;
    const int ci = threadIdx.x & 63, mg = threadIdx.x >> 6;
    const int c = q * 64 + ci;
    float s[8];
    const float bvc = bv[c];
    #pragma unroll
    for (int i = 0; i < 8; ++i) s[i] = bvc * Ksum[b * MDIM + mg * 8 + i];
    #pragma unroll 4
    for (int d = 0; d < CH; ++d) {
        float w = wv[(size_t)c * CH + d];
        #pragma unroll
        for (int i = 0; i < 8; ++i)
            s[i] = fmaf(w, XKR[((size_t)b * MDIM + mg * 8 + i) * CH + d], s[i]);
    }
    short8 p;
    #pragma unroll
    for (int i = 0; i < 8; ++i) p[i] = (short)f2bf(s[i]);
    *(short8*)(KVTb + ((size_t)b * CH + c) * MDIM + mg * 8) = p;
}

// Gram via split-bf16 MFMA, symmetry-aware (SPLIT=16 for CU coverage).
__global__ __launch_bounds__(256, 2) void k_gram(const float* __restrict__ x,
                                                 float* __restrict__ enpart)
{
    __shared__ unsigned short lds[4 * 128 * 72];
    unsigned short* Ah = lds;
    unsigned short* Al = lds + 128 * 72;
    unsigned short* Bh = lds + 2 * 128 * 72;
    unsigned short* Bl = lds + 3 * 128 * 72;

    const int tid = threadIdx.x;
    const int rt = (blockIdx.x == 2) ? 1 : 0;
    const int ct = (blockIdx.x == 0) ? 0 : 1;
    const bool diag = (rt == ct);
    const int sp = blockIdx.y, b = blockIdx.z;
    const int r0 = rt * 128, c0 = ct * 128;
    const float* xb = x + (size_t)b * CH * NPIX;
    const int k0base = sp * KCH;

    unsigned short* Bh_p = diag ? Ah : Bh;
    unsigned short* Bl_p = diag ? Al : Bl;

    const int wave = tid >> 6, lane = tid & 63;
    const int wr = wave >> 1, wc = wave & 1;

    f32x4 acc[4][4];
    #pragma unroll
    for (int i = 0; i < 4; ++i)
        #pragma unroll
        for (int j = 0; j < 4; ++j)
            acc[i][j] = (f32x4){0.f, 0.f, 0.f, 0.f};

    const int oct = tid & 7;
    const int frow = tid >> 3;

    for (int kk = 0; kk < KCH; kk += 64) {
        __syncthreads();
        const int k0 = k0base + kk;
        #pragma unroll
        for (int half = 0; half < 2; ++half) {
            if (half && diag) continue;
            const int rowbase = half ? c0 : r0;
            unsigned short* Hh = half ? Bh : Ah;
            unsigned short* Hl = half ? Bl : Al;
            #pragma unroll
            for (int s = 0; s < 4; ++s) {
                const int r = frow + s * 32;
                const float* src = xb + (size_t)(rowbase + r) * NPIX + k0 + oct * 8;
                float4 v0 = *(const float4*)src;
                float4 v1 = *(const float4*)(src + 4);
                float vv[8] = {v0.x, v0.y, v0.z, v0.w, v1.x, v1.y, v1.z, v1.w};
                short8 ph, pl;
                #pragma unroll
                for (int e = 0; e < 8; ++e) {
                    unsigned short h = f2bf(vv[e]);
                    unsigned short l = f2bf(vv[e] - bf2f(h));
                    ph[e] = (short)h;
                    pl[e] = (short)l;
                }
                *(short8*)&Hh[r * 72 + oct * 8] = ph;
                *(short8*)&Hl[r * 72 + oct * 8] = pl;
            }
        }
        __syncthreads();

        #pragma unroll
        for (int ks2 = 0; ks2 < 2; ++ks2) {
            short8 ah[4], al[4], bh[4], bl[4];
            const int rbase = wr * 64 + (lane & 15);
            const int cbase = wc * 64 + (lane & 15);
            const int koff = ks2 * 32 + (lane >> 4) * 8;
            #pragma unroll
            for (int f = 0; f < 4; ++f) {
                ah[f] = *(const short8*)&Ah[(rbase + f * 16) * 72 + koff];
                al[f] = *(const short8*)&Al[(rbase + f * 16) * 72 + koff];
                bh[f] = *(const short8*)&Bh_p[(cbase + f * 16) * 72 + koff];
                bl[f] = *(const short8*)&Bl_p[(cbase + f * 16) * 72 + koff];
            }
            #pragma unroll
            for (int i = 0; i < 4; ++i)
                #pragma unroll
                for (int j = 0; j < 4; ++j) {
                    acc[i][j] = __builtin_amdgcn_mfma_f32_16x16x32_bf16(ah[i], bh[j], acc[i][j], 0, 0, 0);
                    acc[i][j] = __builtin_amdgcn_mfma_f32_16x16x32_bf16(ah[i], bl[j], acc[i][j], 0, 0, 0);
                    acc[i][j] = __builtin_amdgcn_mfma_f32_16x16x32_bf16(al[i], bh[j], acc[i][j], 0, 0, 0);
                }
        }
    }

    float* ep = enpart + (size_t)(sp * NB + b) * (CH * CH);
    const int rw = (lane >> 4) * 4;
    const int cw = lane & 15;
    #pragma unroll
    for (int i = 0; i < 4; ++i)
        #pragma unroll
        for (int j = 0; j < 4; ++j) {
            const int row = r0 + wr * 64 + i * 16 + rw;
            const int col = c0 + wc * 64 + j * 16 + cw;
            #pragma unroll
            for (int q = 0; q < 4; ++q) {
                float v = acc[i][j][q];
                ep[(size_t)(row + q) * CH + col] = v;
                if (!diag) ep[(size_t)col * CH + (row + q)] = v;
            }
        }
}

// softmin over summed partials; emits bf16 attn [b][c][d].
__global__ void k_softmax(const float* __restrict__ enpart,
                          unsigned short* __restrict__ attnb) {
    const int b = blockIdx.x >> 8, c = blockIdx.x & 255;
    const int d = threadIdx.x;
    __shared__ float red[8];
    float e = 0.f;
    #pragma unroll
    for (int sp = 0; sp < SPLIT; ++sp)
        e += enpart[(size_t)(sp * NB + b) * (CH * CH) + (size_t)c * CH + d];
    float mn = e;
    #pragma unroll
    for (int o = 1; o < 64; o <<= 1) mn = fminf(mn, __shfl_xor(mn, o));
    if ((d & 63) == 0) red[d >> 6] = mn;
    __syncthreads();
    mn = fminf(fminf(red[0], red[1]), fminf(red[2], red[3]));
    float w = expf(mn - e);
    float s = w;
    #pragma unroll
    for (int o = 1; o < 64; o <<= 1) s += __shfl_xor(s, o);
    if ((d & 63) == 0) red[4 + (d >> 6)] = s;
    __syncthreads();
    s = red[4] + red[5] + red[6] + red[7];
    attnb[((size_t)(b * CH) + c) * CH + d] = f2bf(w / s);
}

// out = x + gk*norm*(KV^T·Q) + gc*(attn·X), Q inline via MFMA (pre-split wq).
__global__ __launch_bounds__(256, 2) void k_final(
    const float* __restrict__ x,
    const unsigned short* __restrict__ WQH, const unsigned short* __restrict__ WQL,
    const float* __restrict__ bq,
    const unsigned short* __restrict__ KVTb, const float* __restrict__ Ksum,
    const unsigned short* __restrict__ attnb, const float* __restrict__ gk,
    const float* __restrict__ gc, float* __restrict__ out)
{
    __shared__ uint2 xsTv[4096];            // 32 KB: bf16 xT [n=64][d=256] swizzled
    __shared__ unsigned short qsT[64 * 40]; // 5 KB: bf16 Q [n][m] (pad 40)
    __shared__ float den_s[64];
    unsigned char* xsT = (unsigned char*)xsTv;
    const int b = blockIdx.y, n0 = blockIdx.x * 64, tid = threadIdx.x;
    const int w = tid >> 6, l = tid & 63;
    const int li = l & 15, lg = l >> 4;
    const float* xb = x + (size_t)b * CH * NPIX;

    // ---- stage xT ----
    {
        const int n4 = li * 4;
        const bool o1 = lg & 1, o2 = (lg >> 1) & 1;
        #pragma unroll
        for (int p = 0; p < 16; ++p) {
            const int d0 = w * 64 + p * 4;
            float4 vv = *(const float4*)(xb + (size_t)(d0 + lg) * NPIX + n0 + n4);
            float v0 = vv.x, v1 = vv.y, v2 = vv.z, v3 = vv.w;
            float r1 = __shfl_xor(o1 ? v0 : v1, 16);
            float r2 = __shfl_xor(o1 ? v2 : v3, 16);
            float a0 = o1 ? r1 : v0, a1 = o1 ? v1 : r1;
            float a2 = o1 ? r2 : v2, a3 = o1 ? v3 : r2;
            float r3 = __shfl_xor(o2 ? a0 : a2, 32);
            float r4 = __shfl_xor(o2 ? a1 : a3, 32);
            float b0 = o2 ? r3 : a0, b1 = o2 ? r4 : a1;
            float b2 = o2 ? a2 : r3, b3 = o2 ? a3 : r4;
            const int nl = n4 + lg;
            unsigned lo = (unsigned)f2bf(b0) | ((unsigned)f2bf(b1) << 16);
            unsigned hi = (unsigned)f2bf(b2) | ((unsigned)f2bf(b3) << 16);
            const int off = nl * 512 +
                ((2 * d0) ^ ((nl & 7) << 4) ^ (((nl >> 3) & 1) << 3));
            *(uint2*)(xsT + off) = make_uint2(lo, hi);
        }
    }
    __syncthreads();

    // ---- inline Q via MFMA ----
    {
        f32x4 accq[2];
        accq[0] = (f32x4){0.f, 0.f, 0.f, 0.f};
        accq[1] = (f32x4){0.f, 0.f, 0.f, 0.f};
        const int nf = w * 16 + li;
        const int sw = ((nf & 7) << 4) ^ (((nf >> 3) & 1) << 3);
        #pragma unroll
        for (int kc = 0; kc < 8; ++kc) {
            const int d2 = 2 * (kc * 32 + lg * 8);
            uint2 h0 = *(const uint2*)(xsT + nf * 512 + (d2 ^ sw));
            uint2 h1 = *(const uint2*)(xsT + nf * 512 + ((d2 + 8) ^ sw));
            int4 tmp = make_int4(h0.x, h0.y, h1.x, h1.y);
            short8 bxw = __builtin_bit_cast(short8, tmp);
            #pragma unroll
            for (int i = 0; i < 2; ++i) {
                short8 wh = *(const short8*)(WQH + (size_t)(i * 16 + li) * CH + kc * 32 + lg * 8);
                short8 wl = *(const short8*)(WQL + (size_t)(i * 16 + li) * CH + kc * 32 + lg * 8);
                accq[i] = __builtin_amdgcn_mfma_f32_16x16x32_bf16(wh, bxw, accq[i], 0, 0, 0);
                accq[i] = __builtin_amdgcn_mfma_f32_16x16x32_bf16(wl, bxw, accq[i], 0, 0, 0);
            }
        }
        float den = 0.f;
        #pragma unroll
        for (int i = 0; i < 2; ++i)
            #pragma unroll
            for (int q = 0; q < 4; ++q) {
                const int m = i * 16 + lg * 4 + q;
                float qv = accq[i][q] + bq[m];
                qv = fmaxf(qv, 0.f) + log1pf(expf(-fabsf(qv)));  // softplus
                qsT[(w * 16 + li) * 40 + m] = f2bf(qv);
                den = fmaf(qv, Ksum[b * MDIM + m] + EPSF, den);
            }
        den += __shfl_xor(den, 16);
        den += __shfl_xor(den, 32);
        if (lg == 0) den_s[w * 16 + li] = gk[0] / den;
    }
    __syncthreads();

    f32x4 acc[4][4], accP[4][4];
    #pragma unroll
    for (int i = 0; i < 4; ++i)
        #pragma unroll
        for (int j = 0; j < 4; ++j) {
            acc[i][j] = (f32x4){0.f, 0.f, 0.f, 0.f};
            accP[i][j] = (f32x4){0.f, 0.f, 0.f, 0.f};
        }

    // ---- KAM: P = KV^T · Q ----
    {
        short8 ka[4], qb[4];
        #pragma unroll
        for (int i = 0; i < 4; ++i)
            ka[i] = *(const short8*)(KVTb +
                ((size_t)b * CH + w * 64 + i * 16 + li) * MDIM + lg * 8);
        #pragma unroll
        for (int j = 0; j < 4; ++j)
            qb[j] = *(const short8*)&qsT[(j * 16 + li) * 40 + lg * 8];
        #pragma unroll
        for (int i = 0; i < 4; ++i)
            #pragma unroll
            for (int j = 0; j < 4; ++j)
                accP[i][j] = __builtin_amdgcn_mfma_f32_16x16x32_bf16(ka[i], qb[j], accP[i][j], 0, 0, 0);
    }

    // ---- CAM: attn · X ----
    const unsigned short* ab = attnb + (size_t)b * CH * CH;
    for (int kk = 0; kk < CH; kk += 32) {
        short8 af[4], bx[4];
        #pragma unroll
        for (int i = 0; i < 4; ++i)
            af[i] = *(const short8*)(ab +
                (size_t)(w * 64 + i * 16 + li) * CH + kk + lg * 8);
        #pragma unroll
        for (int j = 0; j < 4; ++j) {
            const int nf = j * 16 + li;
            const int d2 = 2 * (kk + lg * 8);
            const int sw = ((nf & 7) << 4) ^ (((nf >> 3) & 1) << 3);
            uint2 h0 = *(const uint2*)(xsT + nf * 512 + (d2 ^ sw));
            uint2 h1 = *(const uint2*)(xsT + nf * 512 + ((d2 + 8) ^ sw));
            int4 tmp = make_int4(h0.x, h0.y, h1.x, h1.y);
            bx[j] = __builtin_bit_cast(short8, tmp);
        }
        #pragma unroll
        for (int i = 0; i < 4; ++i)
            #pragma unroll
            for (int j = 0; j < 4; ++j)
                acc[i][j] = __builtin_amdgcn_mfma_f32_16x16x32_bf16(af[i], bx[j], acc[i][j], 0, 0, 0);
    }

    // ---- epilogue ----
    const float gcv = gc[0];
    #pragma unroll
    for (int i = 0; i < 4; ++i)
        #pragma unroll
        for (int j = 0; j < 4; ++j) {
            const float nrm = den_s[j * 16 + li];
            #pragma unroll
            for (int q = 0; q < 4; ++q) {
                const int c = w * 64 + i * 16 + lg * 4 + q;
                const size_t idx = (size_t)c * NPIX + n0 + j * 16 + li;
                out[(size_t)b * CH * NPIX + idx] =
                    xb[idx] + nrm * accP[i][j][q] + gcv * acc[i][j][q];
            }
        }
}

extern "C" void kernel_launch(void* const* d_in, const int* in_sizes, int n_in,
                              void* d_out, int out_size, void* d_ws, size_t ws_size,
                              hipStream_t stream)
{
    const float* x  = (const float*)d_in[0];
    const float* wq = (const float*)d_in[1];
    const float* bq = (const float*)d_in[2];
    const float* wk = (const float*)d_in[3];
    const float* bk = (const float*)d_in[4];
    const float* wv = (const float*)d_in[5];
    const float* bv = (const float*)d_in[6];
    const float* gk = (const float*)d_in[7];
    const float* gc = (const float*)d_in[8];
    float* out = (float*)d_out;
    char* wsb = (char*)d_ws;

    unsigned short* ATTB = (unsigned short*)(wsb);
    unsigned short* KVTB = (unsigned short*)(wsb + 1048576);
    float* KSUM = (float*)(wsb + 1179648);
    float* XKR  = (float*)(wsb + 1180672);
    unsigned short* WQH = (unsigned short*)(wsb + 1442816);
    unsigned short* WQL = (unsigned short*)(wsb + 1459200);
    unsigned short* WKH = (unsigned short*)(wsb + 1475584);
    unsigned short* WKL = (unsigned short*)(wsb + 1491968);

    float* xkpart = out;                 // d_out as scratch (overwritten by k_final)
    float* enpart = out + XKPART_SZ;

    hipMemsetAsync(KSUM, 0, 256 * sizeof(float), stream);

    k_prep<<<dim3(32), dim3(256), 0, stream>>>(wq, wk, WQH, WQL, WKH, WKL);
    k_kx<<<dim3(NPIX / 64, NB), dim3(256), 0, stream>>>(x, WKH, WKL, bk, xkpart, KSUM);
    k_gram<<<dim3(3, SPLIT, NB), dim3(256), 0, stream>>>(x, enpart);
    k_xkreduce<<<dim3(NB * MDIM), dim3(CH), 0, stream>>>(xkpart, XKR);
    k_kv<<<dim3(NB, 4), dim3(256), 0, stream>>>(wv, bv, XKR, KSUM, KVTB);
    k_softmax<<<dim3(NB * CH), dim3(CH), 0, stream>>>(enpart, ATTB);
    k_final<<<dim3(NPIX / 64, NB), dim3(256), 0, stream>>>(x, WQH, WQL, bq, KVTB, KSUM,
                                                           ATTB, gk, gc, out);
}

// Round 7
// 311.642 us; speedup vs baseline: 4.7415x; 1.0292x over previous
//
#include <hip/hip_runtime.h>
#include <math.h>

#define NPIX 16384
#define CH 256
#define MDIM 32
#define NB 8
#define EPSF 1e-6f
#define SPLIT 16
#define KCH (NPIX / SPLIT)   // 1024

// ws BYTE layout
//   ATTB @ 0        : bf16 attn [B][C][D]  1,048,576 B
//   KVTB @ 1048576  : bf16 KV^T [B][C][M]    131,072 B
//   KSUM @ 1179648  : f32 [B][M]               1,024 B
//   XKR  @ 1180672  : f32 [B][M][D]          262,144 B
//   WQH  @ 1442816  : bf16 [M][C] 16384 B   (hi split of wq)
//   WQL  @ 1459200  : bf16 [M][C] 16384 B
//   WKH  @ 1475584  : bf16 [M][C] 16384 B
//   WKL  @ 1491968  : bf16 [M][C] 16384 B
// d_out doubles as scratch before k_final overwrites it (stream-ordered):
//   [0, 16777216) floats          xkpart [B][T=256][M][D=256]
//   [16777216, 25165824) floats   enpart [SPLIT=16][B][C][C]
#define XKPART_SZ 16777216ull

typedef short short8 __attribute__((ext_vector_type(8)));
typedef float f32x4 __attribute__((ext_vector_type(4)));

__device__ inline unsigned short f2bf(float v) {
    unsigned u = __builtin_bit_cast(unsigned, v);
    unsigned r = u + 0x7FFFu + ((u >> 16) & 1u);   // RNE (finite inputs)
    return (unsigned short)(r >> 16);
}
__device__ inline float bf2f(unsigned short h) {
    unsigned u = (unsigned)h << 16;
    return __builtin_bit_cast(float, u);
}

// Pre-split wq/wk into hi/lo bf16 pairs.
__global__ void k_prep(const float* __restrict__ wq, const float* __restrict__ wk,
                       unsigned short* __restrict__ WQH, unsigned short* __restrict__ WQL,
                       unsigned short* __restrict__ WKH, unsigned short* __restrict__ WKL)
{
    int i = blockIdx.x * 256 + threadIdx.x;   // 8192 total
    float q = wq[i], k = wk[i];
    unsigned short qh = f2bf(q);
    WQH[i] = qh; WQL[i] = f2bf(q - bf2f(qh));
    unsigned short kh = f2bf(k);
    WKH[i] = kh; WKL[i] = f2bf(k - bf2f(kh));
}

// Single-staging k_kx: x tile staged ONCE (n-major bf16, hashed granules).
//  phase 2: K = softplus(wk·x+bk) MFMA — B-frags gathered per-lane (u16 column
//           walk, ≤2-way banks) from the same tile.
//  phase 3: XK^T = K·x^T MFMA — A-frags are natural b128 row reads.
// No global re-read of x (round-6 re-fetched 64 MB through a cold L2).
// xs elem addr: d*72 + ((g ^ (d&7) ^ ((d>>3)&7))<<3) + (n&7), g = n>>3.
__global__ __launch_bounds__(256, 4) void k_kx(
    const float* __restrict__ x,
    const unsigned short* __restrict__ WKH, const unsigned short* __restrict__ WKL,
    const float* __restrict__ bk,
    float* __restrict__ xkpart, float* __restrict__ Ksum)
{
    __shared__ unsigned short xs[CH * 72];     // 36 KB bf16 x tile [d][64n + hash pad]
    __shared__ unsigned short ksm[MDIM * 72];  // 4.5 KB bf16 softplus(K) [m][n]
    const int b = blockIdx.y, t = blockIdx.x, n0 = t * 64, tid = threadIdx.x;
    const int w = tid >> 6, l = tid & 63;
    const int li = l & 15, lg = l >> 4;
    const float* xb = x + (size_t)b * CH * NPIX;

    // ---- phase 1: stage x tile (coalesced float4 -> bf16, one b128 store) ----
    #pragma unroll
    for (int s = 0; s < 8; ++s) {
        int e8 = tid + s * 256;
        int c = e8 >> 3, j8 = e8 & 7;
        const float* src = xb + (size_t)c * NPIX + n0 + j8 * 8;
        float4 v0 = *(const float4*)src;
        float4 v1 = *(const float4*)(src + 4);
        float vv[8] = {v0.x, v0.y, v0.z, v0.w, v1.x, v1.y, v1.z, v1.w};
        short8 p;
        #pragma unroll
        for (int e = 0; e < 8; ++e) p[e] = (short)f2bf(vv[e]);
        const int g = j8 ^ (c & 7) ^ ((c >> 3) & 7);
        *(short8*)&xs[c * 72 + g * 8] = p;
    }
    __syncthreads();

    // ---- phase 2: K via MFMA; wave w covers n = w*16 + li ----
    {
        f32x4 accq[2];
        accq[0] = (f32x4){0.f, 0.f, 0.f, 0.f};
        accq[1] = (f32x4){0.f, 0.f, 0.f, 0.f};
        const int n = w * 16 + li;
        const int gn = n >> 3, inn = n & 7;
        #pragma unroll
        for (int kc = 0; kc < 8; ++kc) {
            short8 bxw;
            #pragma unroll
            for (int e = 0; e < 8; ++e) {
                const int d = kc * 32 + lg * 8 + e;
                const int g = gn ^ e ^ ((kc * 4 + lg) & 7);
                bxw[e] = (short)xs[d * 72 + g * 8 + inn];
            }
            #pragma unroll
            for (int i = 0; i < 2; ++i) {
                short8 wh = *(const short8*)(WKH + (size_t)(i * 16 + li) * CH + kc * 32 + lg * 8);
                short8 wl = *(const short8*)(WKL + (size_t)(i * 16 + li) * CH + kc * 32 + lg * 8);
                accq[i] = __builtin_amdgcn_mfma_f32_16x16x32_bf16(wh, bxw, accq[i], 0, 0, 0);
                accq[i] = __builtin_amdgcn_mfma_f32_16x16x32_bf16(wl, bxw, accq[i], 0, 0, 0);
            }
        }
        #pragma unroll
        for (int i = 0; i < 2; ++i)
            #pragma unroll
            for (int q = 0; q < 4; ++q) {
                const int m = i * 16 + lg * 4 + q;
                float kv = accq[i][q] + bk[m];
                kv = fmaxf(kv, 0.f) + log1pf(expf(-fabsf(kv)));  // softplus
                ksm[m * 72 + (n ^ ((m & 7) << 3))] = f2bf(kv);
            }
    }
    __syncthreads();

    if (tid < MDIM) {   // Ksum partial for this tile
        float s = 0.f;
        #pragma unroll
        for (int j = 0; j < 64; ++j)
            s += bf2f(ksm[tid * 72 + (j ^ ((tid & 7) << 3))]);
        atomicAdd(&Ksum[b * MDIM + tid], s);
    }

    // ---- phase 3: XK^T[m][d] via MFMA; wave w -> d-range [w*64, w*64+64) ----
    f32x4 axk[4][2];
    #pragma unroll
    for (int i = 0; i < 4; ++i)
        #pragma unroll
        for (int j = 0; j < 2; ++j) axk[i][j] = (f32x4){0.f, 0.f, 0.f, 0.f};

    #pragma unroll
    for (int ks2 = 0; ks2 < 2; ++ks2) {
        const int nc = ks2 * 32 + lg * 8;
        short8 kfr[2];
        #pragma unroll
        for (int j = 0; j < 2; ++j) {
            const int m = j * 16 + li;
            kfr[j] = *(const short8*)&ksm[m * 72 + (nc ^ ((m & 7) << 3))];
        }
        #pragma unroll
        for (int i = 0; i < 4; ++i) {
            const int d = w * 64 + i * 16 + li;
            const int g = (nc >> 3) ^ (d & 7) ^ ((d >> 3) & 7);
            short8 xf = *(const short8*)&xs[d * 72 + g * 8];
            #pragma unroll
            for (int j = 0; j < 2; ++j)
                axk[i][j] = __builtin_amdgcn_mfma_f32_16x16x32_bf16(kfr[j], xf, axk[i][j], 0, 0, 0);
        }
    }

    __syncthreads();                 // xs reads all done — reuse as f32 scratch
    float* xsF = (float*)xs;         // [32 m][256 d], XOR-swizzled (32 KB <= 36 KB)
    #pragma unroll
    for (int i = 0; i < 4; ++i)
        #pragma unroll
        for (int j = 0; j < 2; ++j)
            #pragma unroll
            for (int q = 0; q < 4; ++q) {
                const int m = j * 16 + lg * 4 + q;
                const int d = w * 64 + i * 16 + li;
                xsF[m * 256 + (d ^ ((m & 7) << 2))] = axk[i][j][q];
            }
    __syncthreads();
    float* xp = xkpart + (size_t)(b * 256 + t) * MDIM * CH;
    #pragma unroll 4
    for (int m = 0; m < MDIM; ++m)
        xp[m * CH + tid] = xsF[m * 256 + (tid ^ ((m & 7) << 2))];
}

__global__ void k_xkreduce(const float* __restrict__ xkpart, float* __restrict__ XKR) {
    const int b = blockIdx.x >> 5, m = blockIdx.x & 31, d = threadIdx.x;
    float s = 0.f;
    #pragma unroll 4
    for (int t = 0; t < 256; ++t)
        s += xkpart[(((size_t)b * 256 + t) * MDIM + m) * CH + d];
    XKR[((size_t)b * MDIM + m) * CH + d] = s;
}

// KV^T[c][m] (bf16) = sum_d wv[c][d]*XKR[m][d] + bv[c]*Ksum[m]
__global__ void k_kv(const float* __restrict__ wv, const float* __restrict__ bv,
                     const float* __restrict__ XKR, const float* __restrict__ Ksum,
                     unsigned short* __restrict__ KVTb) {
    const int b = blockIdx.x, q = blockIdx.y;
    const int ci = threadIdx.x & 63, mg = threadIdx.x >> 6;
    const int c = q * 64 + ci;
    float s[8];
    const float bvc = bv[c];
    #pragma unroll
    for (int i = 0; i < 8; ++i) s[i] = bvc * Ksum[b * MDIM + mg * 8 + i];
    #pragma unroll 4
    for (int d = 0; d < CH; ++d) {
        float w = wv[(size_t)c * CH + d];
        #pragma unroll
        for (int i = 0; i < 8; ++i)
            s[i] = fmaf(w, XKR[((size_t)b * MDIM + mg * 8 + i) * CH + d], s[i]);
    }
    short8 p;
    #pragma unroll
    for (int i = 0; i < 8; ++i) p[i] = (short)f2bf(s[i]);
    *(short8*)(KVTb + ((size_t)b * CH + c) * MDIM + mg * 8) = p;
}

// Gram via split-bf16 MFMA, symmetry-aware (SPLIT=16).
__global__ __launch_bounds__(256, 2) void k_gram(const float* __restrict__ x,
                                                 float* __restrict__ enpart)
{
    __shared__ unsigned short lds[4 * 128 * 72];
    unsigned short* Ah = lds;
    unsigned short* Al = lds + 128 * 72;
    unsigned short* Bh = lds + 2 * 128 * 72;
    unsigned short* Bl = lds + 3 * 128 * 72;

    const int tid = threadIdx.x;
    const int rt = (blockIdx.x == 2) ? 1 : 0;
    const int ct = (blockIdx.x == 0) ? 0 : 1;
    const bool diag = (rt == ct);
    const int sp = blockIdx.y, b = blockIdx.z;
    const int r0 = rt * 128, c0 = ct * 128;
    const float* xb = x + (size_t)b * CH * NPIX;
    const int k0base = sp * KCH;

    unsigned short* Bh_p = diag ? Ah : Bh;
    unsigned short* Bl_p = diag ? Al : Bl;

    const int wave = tid >> 6, lane = tid & 63;
    const int wr = wave >> 1, wc = wave & 1;

    f32x4 acc[4][4];
    #pragma unroll
    for (int i = 0; i < 4; ++i)
        #pragma unroll
        for (int j = 0; j < 4; ++j)
            acc[i][j] = (f32x4){0.f, 0.f, 0.f, 0.f};

    const int oct = tid & 7;
    const int frow = tid >> 3;

    for (int kk = 0; kk < KCH; kk += 64) {
        __syncthreads();
        const int k0 = k0base + kk;
        #pragma unroll
        for (int half = 0; half < 2; ++half) {
            if (half && diag) continue;
            const int rowbase = half ? c0 : r0;
            unsigned short* Hh = half ? Bh : Ah;
            unsigned short* Hl = half ? Bl : Al;
            #pragma unroll
            for (int s = 0; s < 4; ++s) {
                const int r = frow + s * 32;
                const float* src = xb + (size_t)(rowbase + r) * NPIX + k0 + oct * 8;
                float4 v0 = *(const float4*)src;
                float4 v1 = *(const float4*)(src + 4);
                float vv[8] = {v0.x, v0.y, v0.z, v0.w, v1.x, v1.y, v1.z, v1.w};
                short8 ph, pl;
                #pragma unroll
                for (int e = 0; e < 8; ++e) {
                    unsigned short h = f2bf(vv[e]);
                    unsigned short l = f2bf(vv[e] - bf2f(h));
                    ph[e] = (short)h;
                    pl[e] = (short)l;
                }
                *(short8*)&Hh[r * 72 + oct * 8] = ph;
                *(short8*)&Hl[r * 72 + oct * 8] = pl;
            }
        }
        __syncthreads();

        #pragma unroll
        for (int ks2 = 0; ks2 < 2; ++ks2) {
            short8 ah[4], al[4], bh[4], bl[4];
            const int rbase = wr * 64 + (lane & 15);
            const int cbase = wc * 64 + (lane & 15);
            const int koff = ks2 * 32 + (lane >> 4) * 8;
            #pragma unroll
            for (int f = 0; f < 4; ++f) {
                ah[f] = *(const short8*)&Ah[(rbase + f * 16) * 72 + koff];
                al[f] = *(const short8*)&Al[(rbase + f * 16) * 72 + koff];
                bh[f] = *(const short8*)&Bh_p[(cbase + f * 16) * 72 + koff];
                bl[f] = *(const short8*)&Bl_p[(cbase + f * 16) * 72 + koff];
            }
            #pragma unroll
            for (int i = 0; i < 4; ++i)
                #pragma unroll
                for (int j = 0; j < 4; ++j) {
                    acc[i][j] = __builtin_amdgcn_mfma_f32_16x16x32_bf16(ah[i], bh[j], acc[i][j], 0, 0, 0);
                    acc[i][j] = __builtin_amdgcn_mfma_f32_16x16x32_bf16(ah[i], bl[j], acc[i][j], 0, 0, 0);
                    acc[i][j] = __builtin_amdgcn_mfma_f32_16x16x32_bf16(al[i], bh[j], acc[i][j], 0, 0, 0);
                }
        }
    }

    float* ep = enpart + (size_t)(sp * NB + b) * (CH * CH);
    const int rw = (lane >> 4) * 4;
    const int cw = lane & 15;
    #pragma unroll
    for (int i = 0; i < 4; ++i)
        #pragma unroll
        for (int j = 0; j < 4; ++j) {
            const int row = r0 + wr * 64 + i * 16 + rw;
            const int col = c0 + wc * 64 + j * 16 + cw;
            #pragma unroll
            for (int q = 0; q < 4; ++q) {
                float v = acc[i][j][q];
                ep[(size_t)(row + q) * CH + col] = v;
                if (!diag) ep[(size_t)col * CH + (row + q)] = v;
            }
        }
}

// softmin over summed partials; emits bf16 attn [b][c][d].
__global__ void k_softmax(const float* __restrict__ enpart,
                          unsigned short* __restrict__ attnb) {
    const int b = blockIdx.x >> 8, c = blockIdx.x & 255;
    const int d = threadIdx.x;
    __shared__ float red[8];
    float e = 0.f;
    #pragma unroll
    for (int sp = 0; sp < SPLIT; ++sp)
        e += enpart[(size_t)(sp * NB + b) * (CH * CH) + (size_t)c * CH + d];
    float mn = e;
    #pragma unroll
    for (int o = 1; o < 64; o <<= 1) mn = fminf(mn, __shfl_xor(mn, o));
    if ((d & 63) == 0) red[d >> 6] = mn;
    __syncthreads();
    mn = fminf(fminf(red[0], red[1]), fminf(red[2], red[3]));
    float w = expf(mn - e);
    float s = w;
    #pragma unroll
    for (int o = 1; o < 64; o <<= 1) s += __shfl_xor(s, o);
    if ((d & 63) == 0) red[4 + (d >> 6)] = s;
    __syncthreads();
    s = red[4] + red[5] + red[6] + red[7];
    attnb[((size_t)(b * CH) + c) * CH + d] = f2bf(w / s);
}

// out = x + gk*norm*(KV^T·Q) + gc*(attn·X), Q inline via MFMA (pre-split wq).
__global__ __launch_bounds__(256, 2) void k_final(
    const float* __restrict__ x,
    const unsigned short* __restrict__ WQH, const unsigned short* __restrict__ WQL,
    const float* __restrict__ bq,
    const unsigned short* __restrict__ KVTb, const float* __restrict__ Ksum,
    const unsigned short* __restrict__ attnb, const float* __restrict__ gk,
    const float* __restrict__ gc, float* __restrict__ out)
{
    __shared__ uint2 xsTv[4096];            // 32 KB: bf16 xT [n=64][d=256] swizzled
    __shared__ unsigned short qsT[64 * 40]; // 5 KB: bf16 Q [n][m] (pad 40)
    __shared__ float den_s[64];
    unsigned char* xsT = (unsigned char*)xsTv;
    const int b = blockIdx.y, n0 = blockIdx.x * 64, tid = threadIdx.x;
    const int w = tid >> 6, l = tid & 63;
    const int li = l & 15, lg = l >> 4;
    const float* xb = x + (size_t)b * CH * NPIX;

    // ---- stage xT ----
    {
        const int n4 = li * 4;
        const bool o1 = lg & 1, o2 = (lg >> 1) & 1;
        #pragma unroll
        for (int p = 0; p < 16; ++p) {
            const int d0 = w * 64 + p * 4;
            float4 vv = *(const float4*)(xb + (size_t)(d0 + lg) * NPIX + n0 + n4);
            float v0 = vv.x, v1 = vv.y, v2 = vv.z, v3 = vv.w;
            float r1 = __shfl_xor(o1 ? v0 : v1, 16);
            float r2 = __shfl_xor(o1 ? v2 : v3, 16);
            float a0 = o1 ? r1 : v0, a1 = o1 ? v1 : r1;
            float a2 = o1 ? r2 : v2, a3 = o1 ? v3 : r2;
            float r3 = __shfl_xor(o2 ? a0 : a2, 32);
            float r4 = __shfl_xor(o2 ? a1 : a3, 32);
            float b0 = o2 ? r3 : a0, b1 = o2 ? r4 : a1;
            float b2 = o2 ? a2 : r3, b3 = o2 ? a3 : r4;
            const int nl = n4 + lg;
            unsigned lo = (unsigned)f2bf(b0) | ((unsigned)f2bf(b1) << 16);
            unsigned hi = (unsigned)f2bf(b2) | ((unsigned)f2bf(b3) << 16);
            const int off = nl * 512 +
                ((2 * d0) ^ ((nl & 7) << 4) ^ (((nl >> 3) & 1) << 3));
            *(uint2*)(xsT + off) = make_uint2(lo, hi);
        }
    }
    __syncthreads();

    // ---- inline Q via MFMA ----
    {
        f32x4 accq[2];
        accq[0] = (f32x4){0.f, 0.f, 0.f, 0.f};
        accq[1] = (f32x4){0.f, 0.f, 0.f, 0.f};
        const int nf = w * 16 + li;
        const int sw = ((nf & 7) << 4) ^ (((nf >> 3) & 1) << 3);
        #pragma unroll
        for (int kc = 0; kc < 8; ++kc) {
            const int d2 = 2 * (kc * 32 + lg * 8);
            uint2 h0 = *(const uint2*)(xsT + nf * 512 + (d2 ^ sw));
            uint2 h1 = *(const uint2*)(xsT + nf * 512 + ((d2 + 8) ^ sw));
            int4 tmp = make_int4(h0.x, h0.y, h1.x, h1.y);
            short8 bxw = __builtin_bit_cast(short8, tmp);
            #pragma unroll
            for (int i = 0; i < 2; ++i) {
                short8 wh = *(const short8*)(WQH + (size_t)(i * 16 + li) * CH + kc * 32 + lg * 8);
                short8 wl = *(const short8*)(WQL + (size_t)(i * 16 + li) * CH + kc * 32 + lg * 8);
                accq[i] = __builtin_amdgcn_mfma_f32_16x16x32_bf16(wh, bxw, accq[i], 0, 0, 0);
                accq[i] = __builtin_amdgcn_mfma_f32_16x16x32_bf16(wl, bxw, accq[i], 0, 0, 0);
            }
        }
        float den = 0.f;
        #pragma unroll
        for (int i = 0; i < 2; ++i)
            #pragma unroll
            for (int q = 0; q < 4; ++q) {
                const int m = i * 16 + lg * 4 + q;
                float qv = accq[i][q] + bq[m];
                qv = fmaxf(qv, 0.f) + log1pf(expf(-fabsf(qv)));  // softplus
                qsT[(w * 16 + li) * 40 + m] = f2bf(qv);
                den = fmaf(qv, Ksum[b * MDIM + m] + EPSF, den);
            }
        den += __shfl_xor(den, 16);
        den += __shfl_xor(den, 32);
        if (lg == 0) den_s[w * 16 + li] = gk[0] / den;
    }
    __syncthreads();

    f32x4 acc[4][4], accP[4][4];
    #pragma unroll
    for (int i = 0; i < 4; ++i)
        #pragma unroll
        for (int j = 0; j < 4; ++j) {
            acc[i][j] = (f32x4){0.f, 0.f, 0.f, 0.f};
            accP[i][j] = (f32x4){0.f, 0.f, 0.f, 0.f};
        }

    // ---- KAM: P = KV^T · Q ----
    {
        short8 ka[4], qb[4];
        #pragma unroll
        for (int i = 0; i < 4; ++i)
            ka[i] = *(const short8*)(KVTb +
                ((size_t)b * CH + w * 64 + i * 16 + li) * MDIM + lg * 8);
        #pragma unroll
        for (int j = 0; j < 4; ++j)
            qb[j] = *(const short8*)&qsT[(j * 16 + li) * 40 + lg * 8];
        #pragma unroll
        for (int i = 0; i < 4; ++i)
            #pragma unroll
            for (int j = 0; j < 4; ++j)
                accP[i][j] = __builtin_amdgcn_mfma_f32_16x16x32_bf16(ka[i], qb[j], accP[i][j], 0, 0, 0);
    }

    // ---- CAM: attn · X ----
    const unsigned short* ab = attnb + (size_t)b * CH * CH;
    for (int kk = 0; kk < CH; kk += 32) {
        short8 af[4], bx[4];
        #pragma unroll
        for (int i = 0; i < 4; ++i)
            af[i] = *(const short8*)(ab +
                (size_t)(w * 64 + i * 16 + li) * CH + kk + lg * 8);
        #pragma unroll
        for (int j = 0; j < 4; ++j) {
            const int nf = j * 16 + li;
            const int d2 = 2 * (kk + lg * 8);
            const int sw = ((nf & 7) << 4) ^ (((nf >> 3) & 1) << 3);
            uint2 h0 = *(const uint2*)(xsT + nf * 512 + (d2 ^ sw));
            uint2 h1 = *(const uint2*)(xsT + nf * 512 + ((d2 + 8) ^ sw));
            int4 tmp = make_int4(h0.x, h0.y, h1.x, h1.y);
            bx[j] = __builtin_bit_cast(short8, tmp);
        }
        #pragma unroll
        for (int i = 0; i < 4; ++i)
            #pragma unroll
            for (int j = 0; j < 4; ++j)
                acc[i][j] = __builtin_amdgcn_mfma_f32_16x16x32_bf16(af[i], bx[j], acc[i][j], 0, 0, 0);
    }

    // ---- epilogue ----
    const float gcv = gc[0];
    #pragma unroll
    for (int i = 0; i < 4; ++i)
        #pragma unroll
        for (int j = 0; j < 4; ++j) {
            const float nrm = den_s[j * 16 + li];
            #pragma unroll
            for (int q = 0; q < 4; ++q) {
                const int c = w * 64 + i * 16 + lg * 4 + q;
                const size_t idx = (size_t)c * NPIX + n0 + j * 16 + li;
                out[(size_t)b * CH * NPIX + idx] =
                    xb[idx] + nrm * accP[i][j][q] + gcv * acc[i][j][q];
            }
        }
}

extern "C" void kernel_launch(void* const* d_in, const int* in_sizes, int n_in,
                              void* d_out, int out_size, void* d_ws, size_t ws_size,
                              hipStream_t stream)
{
    const float* x  = (const float*)d_in[0];
    const float* wq = (const float*)d_in[1];
    const float* bq = (const float*)d_in[2];
    const float* wk = (const float*)d_in[3];
    const float* bk = (const float*)d_in[4];
    const float* wv = (const float*)d_in[5];
    const float* bv = (const float*)d_in[6];
    const float* gk = (const float*)d_in[7];
    const float* gc = (const float*)d_in[8];
    float* out = (float*)d_out;
    char* wsb = (char*)d_ws;

    unsigned short* ATTB = (unsigned short*)(wsb);
    unsigned short* KVTB = (unsigned short*)(wsb + 1048576);
    float* KSUM = (float*)(wsb + 1179648);
    float* XKR  = (float*)(wsb + 1180672);
    unsigned short* WQH = (unsigned short*)(wsb + 1442816);
    unsigned short* WQL = (unsigned short*)(wsb + 1459200);
    unsigned short* WKH = (unsigned short*)(wsb + 1475584);
    unsigned short* WKL = (unsigned short*)(wsb + 1491968);

    float* xkpart = out;                 // d_out as scratch (overwritten by k_final)
    float* enpart = out + XKPART_SZ;

    hipMemsetAsync(KSUM, 0, 256 * sizeof(float), stream);

    k_prep<<<dim3(32), dim3(256), 0, stream>>>(wq, wk, WQH, WQL, WKH, WKL);
    k_kx<<<dim3(NPIX / 64, NB), dim3(256), 0, stream>>>(x, WKH, WKL, bk, xkpart, KSUM);
    k_gram<<<dim3(3, SPLIT, NB), dim3(256), 0, stream>>>(x, enpart);
    k_xkreduce<<<dim3(NB * MDIM), dim3(CH), 0, stream>>>(xkpart, XKR);
    k_kv<<<dim3(NB, 4), dim3(256), 0, stream>>>(wv, bv, XKR, KSUM, KVTB);
    k_softmax<<<dim3(NB * CH), dim3(CH), 0, stream>>>(enpart, ATTB);
    k_final<<<dim3(NPIX / 64, NB), dim3(256), 0, stream>>>(x, WQH, WQL, bq, KVTB, KSUM,
                                                           ATTB, gk, gc, out);
}